// Round 6
// baseline (451.753 us; speedup 1.0000x reference)
//
#include <hip/hip_runtime.h>
#include <hip/hip_fp16.h>

// EquivSetGNN forward, MI355X.
// R19: gathers are ~160us of 303 at ~4.3 TB/s = L3 random-row ceiling (h 12.8MB
// / Xe 6.4MB don't fit a 4MB XCD L2; random indices). Fix: feature-chunked
// layout h[8][NN+1][8] / Xe[8][NE+1][8] / z[8][NN+1][8]; gather blocks take
// chunk = blockIdx%8 (round-robin XCD => chunk region 1.6MB/0.8MB L2-resident
// per XCD). One lane per (chunk,segment), 4-deep pipelined 16B loads -> 256
// independent loads in flight per wave. MM kernels adapted: z chunk-major makes
// az0/az1 fragment loads exactly one chunk (coalesced); h writes chunk-major.
// Everything else = R18 (303us).

constexpr int NN = 100000;   // nodes
constexpr int NE = 50000;    // hyperedges
constexpr int NZ = 1280000;  // incidences
constexpr int NG = 256;      // graphs
constexpr int NTILE = NN / 16;  // 6250 row-tiles of 16
constexpr int CB = 196;         // coarse buckets
constexpr int CAP = 8192;       // bucket region capacity (words)
constexpr int CHUNK = 4000;
constexpr int NBLK_A = NZ / CHUNK;          // 320
constexpr int NBLK_ROW = (NZ + 255) / 256;  // 5000
constexpr int MMGRID = 1024;                // 4 blocks/CU exactly

constexpr size_t NNP8 = (size_t)(NN + 1) * 8;  // halves per h/z chunk region
constexpr size_t NEP8 = (size_t)(NE + 1) * 8;  // halves per Xe chunk region

typedef _Float16 h8 __attribute__((ext_vector_type(8)));
typedef float f4 __attribute__((ext_vector_type(4)));

constexpr int OFF_IN  = 0;
constexpr int OFF_1A  = 8192;
constexpr int OFF_1B  = 12288;
constexpr int OFF_W2  = 16384;
constexpr int OFF_W3  = 24576;
constexpr int OFF_C1  = 28672;
constexpr int OFF_C2  = 32768;
constexpr int WBUF_HALVES = 34816;

__device__ __forceinline__ int lbound(const int* a, int n, int v) {
  int lo = 0, hi = n;
  while (lo < hi) { int m = (lo + hi) >> 1; if (a[m] < v) lo = m + 1; else hi = m; }
  return lo;
}

__device__ __forceinline__ f4 zero4() { f4 z; z[0]=0.f; z[1]=0.f; z[2]=0.f; z[3]=0.f; return z; }

__device__ __forceinline__ h8 ld_a32(const float* p) {
  const f4* v = (const f4*)p;
  f4 lo = v[0], hi = v[1];
  h8 r;
  r[0]=(_Float16)lo[0]; r[1]=(_Float16)lo[1]; r[2]=(_Float16)lo[2]; r[3]=(_Float16)lo[3];
  r[4]=(_Float16)hi[0]; r[5]=(_Float16)hi[1]; r[6]=(_Float16)hi[2]; r[7]=(_Float16)hi[3];
  return r;
}

// LDS transpose read: lane gets row m16, cols q*8..q*8+7 (t0) and +32 (t1),
// via four aligned f4 vector loads (2-way bank alias only -> conflict-free).
__device__ __forceinline__ void lds_tr(const float* __restrict__ myl, int m16, int q,
                                       h8& t0, h8& t1) {
  const f4* rp = (const f4*)(myl + m16 * 68);
  f4 u0 = rp[q * 2], u1 = rp[q * 2 + 1];
  f4 u2 = rp[8 + q * 2], u3 = rp[8 + q * 2 + 1];
#pragma unroll
  for (int j = 0; j < 4; ++j) {
    t0[j] = (_Float16)u0[j]; t0[j + 4] = (_Float16)u1[j];
    t1[j] = (_Float16)u2[j]; t1[j + 4] = (_Float16)u3[j];
  }
}

#define MFMA(a, b, c) __builtin_amdgcn_mfma_f32_16x16x32_f16((a), (b), (c), 0, 0, 0)

// ---- Pass A: coarse bin into fixed-capacity regions, packed ((dst&255)<<24 | src) ----
__global__ void __launch_bounds__(256) binA_k(const int* __restrict__ src,
    const int* __restrict__ dst, int* __restrict__ bcnt, unsigned int* __restrict__ words) {
  __shared__ int cnt[CB];
  __shared__ int base[CB];
  int t = threadIdx.x;
  int start = blockIdx.x * CHUNK;
  for (int i = t; i < CB; i += 256) cnt[i] = 0;
  __syncthreads();
  for (int i = start + t; i < start + CHUNK; i += 256)
    atomicAdd(&cnt[dst[i] >> 8], 1);
  __syncthreads();
  for (int i = t; i < CB; i += 256) base[i] = atomicAdd(&bcnt[i], cnt[i]);
  __syncthreads();
  for (int i = t; i < CB; i += 256) cnt[i] = 0;  // reuse as cursor
  __syncthreads();
  for (int i = start + t; i < start + CHUNK; i += 256) {
    int d = dst[i];
    int b = d >> 8;
    int p = base[b] + atomicAdd(&cnt[b], 1);
    words[(size_t)b * CAP + p] = (unsigned)src[i] | ((unsigned)(d & 255) << 24);
  }
}

// ---- merged: roff | weight prep | dummy-row zero (per-chunk) ----
__global__ void __launch_bounds__(256) prep_misc_k(const int* __restrict__ src,
    int* __restrict__ roff, int* __restrict__ bcnt, int n, int nnz,
    const float* __restrict__ W_in, const float* __restrict__ W1a,
    const float* __restrict__ W1b, const float* __restrict__ W2,
    const float* __restrict__ W3,  const float* __restrict__ Wc1,
    const float* __restrict__ Wc2, _Float16* __restrict__ wbuf,
    __half* __restrict__ hz, __half* __restrict__ Xe) {
  int blk = blockIdx.x;
  if (blk < NBLK_ROW) {
    if (blk == 0 && threadIdx.x < 256) bcnt[threadIdx.x] = 0;
    int i = blk * 256 + threadIdx.x;
    if (i >= nnz) return;
    int s = src[i];
    int prev = (i == 0) ? -1 : src[i - 1];
    for (int v = prev + 1; v <= s; ++v) roff[v] = i;
    if (i == nnz - 1) {
      for (int v = s + 1; v <= n; ++v) roff[v] = nnz;
    }
    return;
  }
  int b = blk - NBLK_ROW;
  if (b == 68) {
    int t = threadIdx.x;
    if (t < 8) {        // zero h/z dummy row (index NN) in chunk t
      int4* pz = (int4*)(hz + (size_t)t * NNP8 + (size_t)NN * 8);
      *pz = int4{0, 0, 0, 0};
    } else if (t < 16) { // zero Xe dummy row (index NE) in chunk t-8
      int4* pz = (int4*)(Xe + (size_t)(t - 8) * NEP8 + (size_t)NE * 8);
      *pz = int4{0, 0, 0, 0};
    }
    return;
  }
  int l = threadIdx.x;
  if (l >= 64) return;
  const float* srcw; int K, J; _Float16* dstw; int tile;
  if      (b < 16) { srcw = W_in; K = 128; J = 64; dstw = wbuf + OFF_IN; tile = b; }
  else if (b < 24) { srcw = W1a;  K = 64;  J = 64; dstw = wbuf + OFF_1A; tile = b - 16; }
  else if (b < 32) { srcw = W1b;  K = 64;  J = 64; dstw = wbuf + OFF_1B; tile = b - 24; }
  else if (b < 48) { srcw = W2;   K = 128; J = 64; dstw = wbuf + OFF_W2; tile = b - 32; }
  else if (b < 56) { srcw = W3;   K = 64;  J = 64; dstw = wbuf + OFF_W3; tile = b - 48; }
  else if (b < 64) { srcw = Wc1;  K = 64;  J = 64; dstw = wbuf + OFF_C1; tile = b - 56; }
  else             { srcw = Wc2;  K = 64;  J = 32; dstw = wbuf + OFF_C2; tile = b - 64; }
  int KS = K / 32;
  int jt = tile / KS, ks = tile % KS;
  int q = l >> 4, m = l & 15;
#pragma unroll
  for (int j = 0; j < 8; ++j)
    dstw[((size_t)tile * 64 + l) * 8 + j] =
        (_Float16)srcw[(size_t)(ks * 32 + q * 8 + j) * J + jt * 16 + m];
}

// ---- merged: binB (blocks<CB) || fused_in_dual (blocks>=CB) ----
union MergedSMem {
  struct { int buf[CAP]; int hist[256]; int sh[256]; int cur[256]; int shb[256]; } b;
  float myl[4][16 * 68];
};

__global__ void __launch_bounds__(256) binB_indual_k(
    const unsigned int* __restrict__ words, const int* __restrict__ bcnt,
    int* __restrict__ off, float* __restrict__ invE, int* __restrict__ csr,
    const float* __restrict__ A, const _Float16* __restrict__ wbuf,
    const float* __restrict__ b_in, const float* __restrict__ b1a,
    const float* __restrict__ b1b, __half* __restrict__ x, __half* __restrict__ h) {
  __shared__ MergedSMem sm;
  if (blockIdx.x < CB) {
    int b = blockIdx.x, t = threadIdx.x;
    int e0 = b << 8;
    int ecnt = min(256, NE - e0);
    int cntb = bcnt[b];
    sm.b.shb[t] = (t < CB) ? bcnt[t] : 0;
    __syncthreads();
    for (int ofs = 1; ofs < 256; ofs <<= 1) {
      int v = (t >= ofs) ? sm.b.shb[t - ofs] : 0;
      __syncthreads();
      sm.b.shb[t] += v;
      __syncthreads();
    }
    int gbase = sm.b.shb[b] - cntb;
    const unsigned int* wp = words + (size_t)b * CAP;
    sm.b.hist[t] = 0;
    __syncthreads();
    for (int i = t; i < cntb; i += 256) atomicAdd(&sm.b.hist[wp[i] >> 24], 1);
    __syncthreads();
    int c = sm.b.hist[t];
    sm.b.sh[t] = c;
    __syncthreads();
    for (int ofs = 1; ofs < 256; ofs <<= 1) {
      int v = (t >= ofs) ? sm.b.sh[t - ofs] : 0;
      __syncthreads();
      sm.b.sh[t] += v;
      __syncthreads();
    }
    int excl = sm.b.sh[t] - c;
    if (t < ecnt) {
      off[e0 + t] = gbase + excl;
      invE[e0 + t] = 1.0f / (float)max(c, 1);
    }
    if (b == CB - 1 && t == 0) off[NE] = NZ;
    sm.b.cur[t] = excl;
    __syncthreads();
    for (int i = t; i < cntb; i += 256) {
      unsigned w = wp[i];
      int s = (int)(w & 0xFFFFFFu);
      int p = atomicAdd(&sm.b.cur[w >> 24], 1);
      if (p < CAP) sm.b.buf[p] = s;
      else csr[gbase + p] = s;  // statistically never
    }
    __syncthreads();
    int lim = min(cntb, CAP);
    for (int i = t; i < lim; i += 256) csr[gbase + i] = sm.b.buf[i];
    return;
  }
  // ---- fused_in_dual branch ----
  int l = threadIdx.x & 63, q = l >> 4, m16 = l & 15, wv = threadIdx.x >> 6;
  int wid = ((blockIdx.x - CB) * 256 + (int)threadIdx.x) >> 6;
  int nw = (MMGRID * 256) >> 6;
  const h8* wip = (const h8*)(wbuf + OFF_IN);
  const h8* wap = (const h8*)(wbuf + OFF_1A);
  const h8* wbp = (const h8*)(wbuf + OFF_1B);
  h8 wi[16], wa[8], wb[8];
#pragma unroll
  for (int f = 0; f < 16; ++f) wi[f] = wip[f * 64 + l];
#pragma unroll
  for (int f = 0; f < 8; ++f) { wa[f] = wap[f * 64 + l]; wb[f] = wbp[f * 64 + l]; }
  float bi[4], ba[4], bb[4];
#pragma unroll
  for (int jt = 0; jt < 4; ++jt) {
    bi[jt] = b_in[jt * 16 + m16]; ba[jt] = b1a[jt * 16 + m16]; bb[jt] = b1b[jt * 16 + m16];
  }
  int ch0 = m16 >> 3, w8 = m16 & 7;
  float* myl = sm.myl[wv];
  for (int t = wid; t < NTILE; t += nw) {
    int rbase = t * 16;
    const float* rp = A + (size_t)(rbase + m16) * 128 + q * 8;
    h8 a0 = ld_a32(rp), a1 = ld_a32(rp + 32), a2 = ld_a32(rp + 64), a3 = ld_a32(rp + 96);
    f4 acc[4];
#pragma unroll
    for (int jt = 0; jt < 4; ++jt) {
      acc[jt] = zero4();
      acc[jt] = MFMA(a0, wi[jt * 4 + 0], acc[jt]);
      acc[jt] = MFMA(a1, wi[jt * 4 + 1], acc[jt]);
      acc[jt] = MFMA(a2, wi[jt * 4 + 2], acc[jt]);
      acc[jt] = MFMA(a3, wi[jt * 4 + 3], acc[jt]);
    }
#pragma unroll
    for (int jt = 0; jt < 4; ++jt)
#pragma unroll
      for (int r = 0; r < 4; ++r) {
        float v = fmaxf(acc[jt][r] + bi[jt], 0.0f);
        x[(size_t)(rbase + q * 4 + r) * 64 + jt * 16 + m16] = __float2half(v);
        myl[(q * 4 + r) * 68 + jt * 16 + m16] = v;
      }
    h8 t0, t1;
    lds_tr(myl, m16, q, t0, t1);
#pragma unroll
    for (int jt = 0; jt < 4; ++jt) {
      acc[jt] = zero4();
      acc[jt] = MFMA(t0, wa[jt * 2 + 0], acc[jt]);
      acc[jt] = MFMA(t1, wa[jt * 2 + 1], acc[jt]);
    }
#pragma unroll
    for (int jt = 0; jt < 4; ++jt)
#pragma unroll
      for (int r = 0; r < 4; ++r)
        myl[(q * 4 + r) * 68 + jt * 16 + m16] = fmaxf(acc[jt][r] + ba[jt], 0.0f);
    lds_tr(myl, m16, q, t0, t1);
#pragma unroll
    for (int jt = 0; jt < 4; ++jt) {
      acc[jt] = zero4();
      acc[jt] = MFMA(t0, wb[jt * 2 + 0], acc[jt]);
      acc[jt] = MFMA(t1, wb[jt * 2 + 1], acc[jt]);
    }
    // h write: chunk-major [8][NN+1][8]
#pragma unroll
    for (int jt = 0; jt < 4; ++jt) {
      __half* hb = h + (size_t)(jt * 2 + ch0) * NNP8 + w8;
#pragma unroll
      for (int r = 0; r < 4; ++r)
        hb[(size_t)(rbase + q * 4 + r) * 8] = __float2half(acc[jt][r] + bb[jt]);
    }
  }
}

// ---- per-lane pipelined segment-mean over one feature chunk (16B/row-read) ----
__device__ __forceinline__ void seg_lane(const __half* __restrict__ rows,
    const int* __restrict__ idxArr, int lo, int hi, int zrow, float inv,
    __half* __restrict__ outp, int gid) {
  float acc[8];
#pragma unroll
  for (int j = 0; j < 8; ++j) acc[j] = 0.0f;
  int n = hi - lo;
  if (n > 0) {
    int lim = hi - 1;
    int i = lo;
    int j0 = idxArr[i];
    int j1 = idxArr[min(i + 1, lim)]; j1 = (i + 1 <= lim) ? j1 : zrow;
    int j2 = idxArr[min(i + 2, lim)]; j2 = (i + 2 <= lim) ? j2 : zrow;
    int j3 = idxArr[min(i + 3, lim)]; j3 = (i + 3 <= lim) ? j3 : zrow;
    int nb = (n + 3) >> 2;
    for (int b = 0; b < nb; ++b) {
      h8 v0 = *(const h8*)(rows + (size_t)j0 * 8);
      h8 v1 = *(const h8*)(rows + (size_t)j1 * 8);
      h8 v2 = *(const h8*)(rows + (size_t)j2 * 8);
      h8 v3 = *(const h8*)(rows + (size_t)j3 * 8);
      i += 4;
      int n0 = idxArr[min(i, lim)];     n0 = (i     <= lim) ? n0 : zrow;
      int n1 = idxArr[min(i + 1, lim)]; n1 = (i + 1 <= lim) ? n1 : zrow;
      int n2 = idxArr[min(i + 2, lim)]; n2 = (i + 2 <= lim) ? n2 : zrow;
      int n3 = idxArr[min(i + 3, lim)]; n3 = (i + 3 <= lim) ? n3 : zrow;
#pragma unroll
      for (int j = 0; j < 8; ++j)
        acc[j] += ((float)v0[j] + (float)v1[j]) + ((float)v2[j] + (float)v3[j]);
      j0 = n0; j1 = n1; j2 = n2; j3 = n3;
    }
  }
  h8 o;
#pragma unroll
  for (int j = 0; j < 8; ++j) o[j] = (_Float16)(acc[j] * inv);
  *(h8*)(outp + (size_t)gid * 8) = o;
}

// ---- V->E pull: chunk = blockIdx%8 (XCD-affine), one lane per segment ----
__global__ void __launch_bounds__(256) ve_pull_k(const __half* __restrict__ hc,
    const int* __restrict__ csr, const int* __restrict__ off,
    const float* __restrict__ invE, __half* __restrict__ Xec) {
  int chunk = blockIdx.x & 7;
  int seg = (blockIdx.x >> 3) * 256 + threadIdx.x;
  if (seg >= NE) return;
  const __half* rows = hc + (size_t)chunk * NNP8;
  __half* outp = Xec + (size_t)chunk * NEP8;
  seg_lane(rows, csr, off[seg], off[seg + 1], NN, invE[seg], outp, seg);
}

// ---- E->V pull: chunk = blockIdx%8, one lane per node ----
__global__ void __launch_bounds__(256) zgather_k(const __half* __restrict__ Xec,
    const int* __restrict__ dstArr, const int* __restrict__ roff,
    __half* __restrict__ zc) {
  int chunk = blockIdx.x & 7;
  int nd = (blockIdx.x >> 3) * 256 + threadIdx.x;
  if (nd >= NN) return;
  const __half* rows = Xec + (size_t)chunk * NEP8;
  __half* outp = zc + (size_t)chunk * NNP8;
  int lo = roff[nd], hi = roff[nd + 1];
  float inv = (hi > lo) ? 1.0f / (float)(hi - lo) : 0.0f;
  seg_lane(rows, dstArr, lo, hi, NE, inv, outp, nd);
}

// ---- fused: layer-1 catmm_w3 + layer-2 W1 MLP (z/h alias, tile-local) ----
__global__ void __launch_bounds__(256) fused_cat_dual(const __half* xin,
    const __half* z, const __half* x0,
    const int* __restrict__ roff, const _Float16* __restrict__ wbuf,
    const float* __restrict__ b2, const float* __restrict__ b3,
    const float* __restrict__ b1a, const float* __restrict__ b1b,
    __half* __restrict__ xout, __half* h, int ntiles) {
  __shared__ float lds[4][16 * 68];
  int l = threadIdx.x & 63, q = l >> 4, m16 = l & 15, wv = threadIdx.x >> 6;
  int wid = (blockIdx.x * blockDim.x + threadIdx.x) >> 6;
  int nw = (gridDim.x * blockDim.x) >> 6;
  const h8* w2p = (const h8*)(wbuf + OFF_W2);
  const h8* w3p = (const h8*)(wbuf + OFF_W3);
  const h8* wap = (const h8*)(wbuf + OFF_1A);
  const h8* wbp = (const h8*)(wbuf + OFF_1B);
  h8 w2[16], w3[8], wa[8], wb[8];
#pragma unroll
  for (int f = 0; f < 16; ++f) w2[f] = w2p[f * 64 + l];
#pragma unroll
  for (int f = 0; f < 8; ++f) { w3[f] = w3p[f * 64 + l]; wa[f] = wap[f * 64 + l]; wb[f] = wbp[f * 64 + l]; }
  float bv2[4], bv3[4], ba[4], bb[4];
#pragma unroll
  for (int jt = 0; jt < 4; ++jt) {
    bv2[jt] = b2[jt * 16 + m16]; bv3[jt] = b3[jt * 16 + m16];
    ba[jt] = b1a[jt * 16 + m16]; bb[jt] = b1b[jt * 16 + m16];
  }
  int ch0 = m16 >> 3, w8 = m16 & 7;
  float* myl = lds[wv];
  for (int t = wid; t < ntiles; t += nw) {
    int rbase = t * 16;
    const __half* rp = xin + (size_t)(rbase + m16) * 64 + q * 8;
    h8 a0 = *(const h8*)rp, a1 = *(const h8*)(rp + 32);
    // z chunk-major: az0 = chunk q, az1 = chunk q+4, row rbase+m16
    const __half* zq = z + (size_t)q * NNP8 + (size_t)(rbase + m16) * 8;
    h8 az0 = *(const h8*)zq, az1 = *(const h8*)(zq + 4 * NNP8);
    f4 acc[4];
#pragma unroll
    for (int jt = 0; jt < 4; ++jt) {
      acc[jt] = zero4();
      acc[jt] = MFMA(a0,  w2[jt * 4 + 0], acc[jt]);
      acc[jt] = MFMA(a1,  w2[jt * 4 + 1], acc[jt]);
      acc[jt] = MFMA(az0, w2[jt * 4 + 2], acc[jt]);
      acc[jt] = MFMA(az1, w2[jt * 4 + 3], acc[jt]);
    }
#pragma unroll
    for (int r = 0; r < 4; ++r) {
      int row = rbase + q * 4 + r;
      float msk = (roff[row + 1] > roff[row]) ? 0.5f : 0.0f;
#pragma unroll
      for (int jt = 0; jt < 4; ++jt) {
        float val = acc[jt][r] + bv2[jt];
        float x0v = __half2float(x0[(size_t)row * 64 + jt * 16 + m16]);
        myl[(q * 4 + r) * 68 + jt * 16 + m16] = fmaf(msk, val, 0.5f * x0v);
      }
    }
    h8 t0, t1;
    lds_tr(myl, m16, q, t0, t1);
#pragma unroll
    for (int jt = 0; jt < 4; ++jt) {
      acc[jt] = zero4();
      acc[jt] = MFMA(t0, w3[jt * 2 + 0], acc[jt]);
      acc[jt] = MFMA(t1, w3[jt * 2 + 1], acc[jt]);
    }
#pragma unroll
    for (int jt = 0; jt < 4; ++jt)
#pragma unroll
      for (int r = 0; r < 4; ++r) {
        float v = fmaxf(acc[jt][r] + bv3[jt], 0.0f);
        xout[(size_t)(rbase + q * 4 + r) * 64 + jt * 16 + m16] = __float2half(v);
        myl[(q * 4 + r) * 68 + jt * 16 + m16] = v;
      }
    lds_tr(myl, m16, q, t0, t1);
#pragma unroll
    for (int jt = 0; jt < 4; ++jt) {
      acc[jt] = zero4();
      acc[jt] = MFMA(t0, wa[jt * 2 + 0], acc[jt]);
      acc[jt] = MFMA(t1, wa[jt * 2 + 1], acc[jt]);
    }
#pragma unroll
    for (int jt = 0; jt < 4; ++jt)
#pragma unroll
      for (int r = 0; r < 4; ++r)
        myl[(q * 4 + r) * 68 + jt * 16 + m16] = fmaxf(acc[jt][r] + ba[jt], 0.0f);
    lds_tr(myl, m16, q, t0, t1);
#pragma unroll
    for (int jt = 0; jt < 4; ++jt) {
      acc[jt] = zero4();
      acc[jt] = MFMA(t0, wb[jt * 2 + 0], acc[jt]);
      acc[jt] = MFMA(t1, wb[jt * 2 + 1], acc[jt]);
    }
    // h write: chunk-major (reads of z for this tile happened above)
#pragma unroll
    for (int jt = 0; jt < 4; ++jt) {
      __half* hb = h + (size_t)(jt * 2 + ch0) * NNP8 + w8;
#pragma unroll
      for (int r = 0; r < 4; ++r)
        hb[(size_t)(rbase + q * 4 + r) * 8] = __float2half(acc[jt][r] + bb[jt]);
    }
  }
}

// ---- fused: layer-2 catmm_w3 + classifier (logits to outc, row-major) ----
__global__ void __launch_bounds__(256) fused_cat_cls(const __half* __restrict__ xin,
    const __half* __restrict__ z, const __half* __restrict__ x0,
    const int* __restrict__ roff, const _Float16* __restrict__ wbuf,
    const float* __restrict__ b2, const float* __restrict__ b3,
    const float* __restrict__ bc1, const float* __restrict__ bc2,
    __half* __restrict__ out, int ntiles) {
  __shared__ float lds[4][16 * 68];
  int l = threadIdx.x & 63, q = l >> 4, m16 = l & 15, wv = threadIdx.x >> 6;
  int wid = (blockIdx.x * blockDim.x + threadIdx.x) >> 6;
  int nw = (gridDim.x * blockDim.x) >> 6;
  const h8* w2p = (const h8*)(wbuf + OFF_W2);
  const h8* w3p = (const h8*)(wbuf + OFF_W3);
  const h8* wc1p = (const h8*)(wbuf + OFF_C1);
  const h8* wc2p = (const h8*)(wbuf + OFF_C2);
  h8 w2[16], w3[8], wc1[8], wc2[4];
#pragma unroll
  for (int f = 0; f < 16; ++f) w2[f] = w2p[f * 64 + l];
#pragma unroll
  for (int f = 0; f < 8; ++f) { w3[f] = w3p[f * 64 + l]; wc1[f] = wc1p[f * 64 + l]; }
#pragma unroll
  for (int f = 0; f < 4; ++f) wc2[f] = wc2p[f * 64 + l];
  float bv2[4], bv3[4], bv1[4], bvo[2];
#pragma unroll
  for (int jt = 0; jt < 4; ++jt) {
    bv2[jt] = b2[jt * 16 + m16]; bv3[jt] = b3[jt * 16 + m16]; bv1[jt] = bc1[jt * 16 + m16];
  }
#pragma unroll
  for (int jt = 0; jt < 2; ++jt) bvo[jt] = bc2[jt * 16 + m16];
  float* myl = lds[wv];
  for (int t = wid; t < ntiles; t += nw) {
    int rbase = t * 16;
    const __half* rp = xin + (size_t)(rbase + m16) * 64 + q * 8;
    h8 a0 = *(const h8*)rp, a1 = *(const h8*)(rp + 32);
    const __half* zq = z + (size_t)q * NNP8 + (size_t)(rbase + m16) * 8;
    h8 az0 = *(const h8*)zq, az1 = *(const h8*)(zq + 4 * NNP8);
    f4 acc[4];
#pragma unroll
    for (int jt = 0; jt < 4; ++jt) {
      acc[jt] = zero4();
      acc[jt] = MFMA(a0,  w2[jt * 4 + 0], acc[jt]);
      acc[jt] = MFMA(a1,  w2[jt * 4 + 1], acc[jt]);
      acc[jt] = MFMA(az0, w2[jt * 4 + 2], acc[jt]);
      acc[jt] = MFMA(az1, w2[jt * 4 + 3], acc[jt]);
    }
#pragma unroll
    for (int r = 0; r < 4; ++r) {
      int row = rbase + q * 4 + r;
      float msk = (roff[row + 1] > roff[row]) ? 0.5f : 0.0f;
#pragma unroll
      for (int jt = 0; jt < 4; ++jt) {
        float val = acc[jt][r] + bv2[jt];
        float x0v = __half2float(x0[(size_t)row * 64 + jt * 16 + m16]);
        myl[(q * 4 + r) * 68 + jt * 16 + m16] = fmaf(msk, val, 0.5f * x0v);
      }
    }
    h8 t0, t1;
    lds_tr(myl, m16, q, t0, t1);
#pragma unroll
    for (int jt = 0; jt < 4; ++jt) {
      acc[jt] = zero4();
      acc[jt] = MFMA(t0, w3[jt * 2 + 0], acc[jt]);
      acc[jt] = MFMA(t1, w3[jt * 2 + 1], acc[jt]);
    }
#pragma unroll
    for (int jt = 0; jt < 4; ++jt)
#pragma unroll
      for (int r = 0; r < 4; ++r)
        myl[(q * 4 + r) * 68 + jt * 16 + m16] = fmaxf(acc[jt][r] + bv3[jt], 0.0f);
    lds_tr(myl, m16, q, t0, t1);
#pragma unroll
    for (int jt = 0; jt < 4; ++jt) {
      acc[jt] = zero4();
      acc[jt] = MFMA(t0, wc1[jt * 2 + 0], acc[jt]);
      acc[jt] = MFMA(t1, wc1[jt * 2 + 1], acc[jt]);
    }
#pragma unroll
    for (int jt = 0; jt < 4; ++jt)
#pragma unroll
      for (int r = 0; r < 4; ++r)
        myl[(q * 4 + r) * 68 + jt * 16 + m16] = fmaxf(acc[jt][r] + bv1[jt], 0.0f);
    lds_tr(myl, m16, q, t0, t1);
    f4 o[2];
#pragma unroll
    for (int jt = 0; jt < 2; ++jt) {
      o[jt] = zero4();
      o[jt] = MFMA(t0, wc2[jt * 2 + 0], o[jt]);
      o[jt] = MFMA(t1, wc2[jt * 2 + 1], o[jt]);
    }
#pragma unroll
    for (int jt = 0; jt < 2; ++jt)
#pragma unroll
      for (int r = 0; r < 4; ++r)
        out[(size_t)(rbase + q * 4 + r) * 32 + jt * 16 + m16] =
            __float2half(o[jt][r] + bvo[jt]);
  }
}

// ---- per-graph mean readout; fp16 input ----
__global__ void __launch_bounds__(256) readout_k(const __half* __restrict__ xc,
    const int* __restrict__ batch, int n, float* __restrict__ out) {
  __shared__ float part[8][32];
  int g = blockIdx.x;
  int lo = lbound(batch, n, g);
  int hi = lbound(batch, n, g + 1);
  int j = threadIdx.x & 31, r = threadIdx.x >> 5;
  float acc = 0.0f;
  for (int i = lo + r; i < hi; i += 8) acc += __half2float(xc[(size_t)i * 32 + j]);
  part[r][j] = acc;
  __syncthreads();
  if (threadIdx.x < 32) {
    float s = 0.0f;
#pragma unroll
    for (int rr = 0; rr < 8; ++rr) s += part[rr][j];
    out[g * 32 + j] = (hi > lo) ? s / (float)(hi - lo) : 0.0f;
  }
}

extern "C" void kernel_launch(void* const* d_in, const int* in_sizes, int n_in,
                              void* d_out, int out_size, void* d_ws, size_t ws_size,
                              hipStream_t stream) {
  const float* X    = (const float*)d_in[0];
  const int*   src  = (const int*)d_in[1];
  const int*   dst  = (const int*)d_in[2];
  const int*   batch= (const int*)d_in[3];
  const float* W_in = (const float*)d_in[4];
  const float* b_in = (const float*)d_in[5];
  const float* W1a  = (const float*)d_in[6];
  const float* b1a  = (const float*)d_in[7];
  const float* W1b  = (const float*)d_in[8];
  const float* b1b  = (const float*)d_in[9];
  const float* W2   = (const float*)d_in[10];
  const float* b2   = (const float*)d_in[11];
  const float* W3   = (const float*)d_in[12];
  const float* b3   = (const float*)d_in[13];
  const float* Wc1  = (const float*)d_in[14];
  const float* bc1  = (const float*)d_in[15];
  const float* Wc2  = (const float*)d_in[16];
  const float* bc2  = (const float*)d_in[17];
  float* out = (float*)d_out;

  // workspace layout (~57 MB)
  float* p  = (float*)d_ws;
  __half* xA = (__half*)p; p += (size_t)NN * 32;        // x0 / layer-1 x (row-major)
  __half* xB = (__half*)p; p += (size_t)NN * 32;        // layer-1 out / layer-2 x (row-major)
  __half* hz = (__half*)p; p += (size_t)(NN + 2) * 32;  // h/z chunk-major [8][NN+1][8]
  __half* Xe = (__half*)p; p += (size_t)(NE + 2) * 32;  // Xe chunk-major [8][NE+1][8]; outc at end
  float* invE = p; p += NE;
  _Float16* wbuf = (_Float16*)p; p += WBUF_HALVES / 2 + 16;
  int* q     = (int*)p;
  int* off   = q; q += NE + 1;
  int* bcnt  = q; q += 256;
  int* roff  = q; q += NN + 1;
  int* csr   = q; q += NZ;        // 5.12 MB
  unsigned int* words = (unsigned int*)q; q += CB * CAP;  // 6.4 MB
  __half* h = hz;
  __half* z = hz;            // alias: h fully consumed before z written
  __half* outc = Xe;         // alias: Xe dead after layer-2 zgather

  // roff + weight prep + per-chunk dummy-row zero
  prep_misc_k<<<NBLK_ROW + 69, 256, 0, stream>>>(src, roff, bcnt, NN, NZ,
      W_in, W1a, W1b, W2, W3, Wc1, Wc2, wbuf, hz, Xe);
  binA_k<<<NBLK_A, 256, 0, stream>>>(src, dst, bcnt, words);

  // binB || layer-1 front half (x=x0=xA, h) in one dispatch
  binB_indual_k<<<CB + MMGRID, 256, 0, stream>>>(words, bcnt, off, invE, csr,
      X, wbuf, b_in, b1a, b1b, xA, h);

  int veg = ((NE + 255) / 256) * 8;   // 1568: chunk = bid%8 (XCD-affine)
  int zgg = ((NN + 255) / 256) * 8;   // 3128
  ve_pull_k<<<veg, 256, 0, stream>>>(h, csr, off, invE, Xe);
  zgather_k<<<zgg, 256, 0, stream>>>(Xe, dst, roff, z);

  // layer-1 back half + layer-2 front half
  fused_cat_dual<<<MMGRID, 256, 0, stream>>>(xA, z, xA, roff, wbuf, b2, b3, b1a, b1b,
                                             xB, h, NTILE);
  ve_pull_k<<<veg, 256, 0, stream>>>(h, csr, off, invE, Xe);
  zgather_k<<<zgg, 256, 0, stream>>>(Xe, dst, roff, z);

  // layer-2 back half + classifier: logits to outc
  fused_cat_cls<<<MMGRID, 256, 0, stream>>>(xB, z, xA, roff, wbuf, b2, b3, bc1, bc2,
                                            outc, NTILE);
  readout_k<<<NG, 256, 0, stream>>>(outc, batch, NN, out);
}

// Round 7
// 431.515 us; speedup vs baseline: 1.0469x; 1.0469x over previous
//
#include <hip/hip_runtime.h>
#include <hip/hip_fp16.h>

// EquivSetGNN forward, MI355X.
// R20: revert R19's chunked gather (64us: 8x request inflation at 16B granules
// hit the ~0.25 req/cy/CU wall; keep 128B transactions). Base = R18 (303us).
// New: zgather is tile-local w.r.t. the consuming cat kernel -> fuse it in:
// each wave gathers its 16 nodes' z (8-lane groups, Xe[dst] 128B reads) into
// its LDS slice, then runs cat+W3+{dual|cls} consuming z via lds_tr. Deletes
// 2 dispatches + z round-trip (25.6MB/layer) and overlaps gather loads with
// MM work across waves. ve_pull unchanged (needs globally-complete input).
// Fused kernels: __launch_bounds__(256,3), grid 782 (2 tiles/wave, no tail).
// Logits -> hz region (Xe now read by fused cls).

constexpr int NN = 100000;   // nodes
constexpr int NE = 50000;    // hyperedges
constexpr int NZ = 1280000;  // incidences
constexpr int NG = 256;      // graphs
constexpr int NTILE = NN / 16;  // 6250 row-tiles of 16
constexpr int CB = 196;         // coarse buckets
constexpr int CAP = 8192;       // bucket region capacity (words)
constexpr int CHUNK = 4000;
constexpr int NBLK_A = NZ / CHUNK;          // 320
constexpr int NBLK_ROW = (NZ + 255) / 256;  // 5000
constexpr int MMGRID = 1024;                // in_dual grid (4 blocks/CU)
constexpr int CATGRID = 782;                // fused cat grids: 3128 waves x 2 tiles

typedef _Float16 h8 __attribute__((ext_vector_type(8)));
typedef float f4 __attribute__((ext_vector_type(4)));

constexpr int OFF_IN  = 0;
constexpr int OFF_1A  = 8192;
constexpr int OFF_1B  = 12288;
constexpr int OFF_W2  = 16384;
constexpr int OFF_W3  = 24576;
constexpr int OFF_C1  = 28672;
constexpr int OFF_C2  = 32768;
constexpr int WBUF_HALVES = 34816;

__device__ __forceinline__ int lbound(const int* a, int n, int v) {
  int lo = 0, hi = n;
  while (lo < hi) { int m = (lo + hi) >> 1; if (a[m] < v) lo = m + 1; else hi = m; }
  return lo;
}

__device__ __forceinline__ f4 zero4() { f4 z; z[0]=0.f; z[1]=0.f; z[2]=0.f; z[3]=0.f; return z; }

__device__ __forceinline__ h8 ld_a32(const float* p) {
  const f4* v = (const f4*)p;
  f4 lo = v[0], hi = v[1];
  h8 r;
  r[0]=(_Float16)lo[0]; r[1]=(_Float16)lo[1]; r[2]=(_Float16)lo[2]; r[3]=(_Float16)lo[3];
  r[4]=(_Float16)hi[0]; r[5]=(_Float16)hi[1]; r[6]=(_Float16)hi[2]; r[7]=(_Float16)hi[3];
  return r;
}

// LDS transpose read: lane gets row m16, cols q*8..q*8+7 (t0) and +32 (t1),
// via four aligned f4 vector loads (2-way bank alias only -> conflict-free).
__device__ __forceinline__ void lds_tr(const float* __restrict__ myl, int m16, int q,
                                       h8& t0, h8& t1) {
  const f4* rp = (const f4*)(myl + m16 * 68);
  f4 u0 = rp[q * 2], u1 = rp[q * 2 + 1];
  f4 u2 = rp[8 + q * 2], u3 = rp[8 + q * 2 + 1];
#pragma unroll
  for (int j = 0; j < 4; ++j) {
    t0[j] = (_Float16)u0[j]; t0[j + 4] = (_Float16)u1[j];
    t1[j] = (_Float16)u2[j]; t1[j + 4] = (_Float16)u3[j];
  }
}

#define MFMA(a, b, c) __builtin_amdgcn_mfma_f32_16x16x32_f16((a), (b), (c), 0, 0, 0)

// ---- in-tile z gather: group g handles nodes rbase+2g+{0,1}; lane covers 8
// feats; writes fp32 z rows into the wave's LDS tile (row-major [16][68]).
__device__ __forceinline__ void tile_zgather(const __half* __restrict__ Xe,
    const int* __restrict__ dstArr, const int* __restrict__ roff,
    int rbase, int l, float* __restrict__ myl) {
  int g = l >> 3, c = l & 7;
#pragma unroll
  for (int k = 0; k < 2; ++k) {
    int nd = rbase + g * 2 + k;
    int lo = roff[nd], hi = roff[nd + 1];
    float acc[8];
#pragma unroll
    for (int j = 0; j < 8; ++j) acc[j] = 0.0f;
    int i = lo;
    for (; i + 1 < hi; i += 2) {
      int r0 = dstArr[i], r1 = dstArr[i + 1];
      h8 v0 = *(const h8*)(Xe + (size_t)r0 * 64 + c * 8);
      h8 v1 = *(const h8*)(Xe + (size_t)r1 * 64 + c * 8);
#pragma unroll
      for (int j = 0; j < 8; ++j) acc[j] += (float)v0[j] + (float)v1[j];
    }
    if (i < hi) {
      int r = dstArr[i];
      h8 v = *(const h8*)(Xe + (size_t)r * 64 + c * 8);
#pragma unroll
      for (int j = 0; j < 8; ++j) acc[j] += (float)v[j];
    }
    float inv = (hi > lo) ? 1.0f / (float)(hi - lo) : 0.0f;
    f4* wp = (f4*)(myl + (g * 2 + k) * 68 + c * 8);
    f4 w0, w1;
#pragma unroll
    for (int j = 0; j < 4; ++j) { w0[j] = acc[j] * inv; w1[j] = acc[j + 4] * inv; }
    wp[0] = w0; wp[1] = w1;
  }
}

// ---- Pass A: coarse bin into fixed-capacity regions, packed ((dst&255)<<24 | src) ----
__global__ void __launch_bounds__(256) binA_k(const int* __restrict__ src,
    const int* __restrict__ dst, int* __restrict__ bcnt, unsigned int* __restrict__ words) {
  __shared__ int cnt[CB];
  __shared__ int base[CB];
  int t = threadIdx.x;
  int start = blockIdx.x * CHUNK;
  for (int i = t; i < CB; i += 256) cnt[i] = 0;
  __syncthreads();
  for (int i = start + t; i < start + CHUNK; i += 256)
    atomicAdd(&cnt[dst[i] >> 8], 1);
  __syncthreads();
  for (int i = t; i < CB; i += 256) base[i] = atomicAdd(&bcnt[i], cnt[i]);
  __syncthreads();
  for (int i = t; i < CB; i += 256) cnt[i] = 0;  // reuse as cursor
  __syncthreads();
  for (int i = start + t; i < start + CHUNK; i += 256) {
    int d = dst[i];
    int b = d >> 8;
    int p = base[b] + atomicAdd(&cnt[b], 1);
    words[(size_t)b * CAP + p] = (unsigned)src[i] | ((unsigned)(d & 255) << 24);
  }
}

// ---- merged: roff | weight prep | dummy-row zero ----
__global__ void __launch_bounds__(256) prep_misc_k(const int* __restrict__ src,
    int* __restrict__ roff, int* __restrict__ bcnt, int n, int nnz,
    const float* __restrict__ W_in, const float* __restrict__ W1a,
    const float* __restrict__ W1b, const float* __restrict__ W2,
    const float* __restrict__ W3,  const float* __restrict__ Wc1,
    const float* __restrict__ Wc2, _Float16* __restrict__ wbuf,
    __half* __restrict__ hz) {
  int blk = blockIdx.x;
  if (blk < NBLK_ROW) {
    if (blk == 0 && threadIdx.x < 256) bcnt[threadIdx.x] = 0;
    int i = blk * 256 + threadIdx.x;
    if (i >= nnz) return;
    int s = src[i];
    int prev = (i == 0) ? -1 : src[i - 1];
    for (int v = prev + 1; v <= s; ++v) roff[v] = i;
    if (i == nnz - 1) {
      for (int v = s + 1; v <= n; ++v) roff[v] = nnz;
    }
    return;
  }
  int b = blk - NBLK_ROW;
  if (b == 68) {
    int t = threadIdx.x;
    if (t < 32) ((float*)(hz + (size_t)NN * 64))[t] = 0.0f;  // h dummy row NN
    return;
  }
  int l = threadIdx.x;
  if (l >= 64) return;
  const float* srcw; int K, J; _Float16* dstw; int tile;
  if      (b < 16) { srcw = W_in; K = 128; J = 64; dstw = wbuf + OFF_IN; tile = b; }
  else if (b < 24) { srcw = W1a;  K = 64;  J = 64; dstw = wbuf + OFF_1A; tile = b - 16; }
  else if (b < 32) { srcw = W1b;  K = 64;  J = 64; dstw = wbuf + OFF_1B; tile = b - 24; }
  else if (b < 48) { srcw = W2;   K = 128; J = 64; dstw = wbuf + OFF_W2; tile = b - 32; }
  else if (b < 56) { srcw = W3;   K = 64;  J = 64; dstw = wbuf + OFF_W3; tile = b - 48; }
  else if (b < 64) { srcw = Wc1;  K = 64;  J = 64; dstw = wbuf + OFF_C1; tile = b - 56; }
  else             { srcw = Wc2;  K = 64;  J = 32; dstw = wbuf + OFF_C2; tile = b - 64; }
  int KS = K / 32;
  int jt = tile / KS, ks = tile % KS;
  int q = l >> 4, m = l & 15;
#pragma unroll
  for (int j = 0; j < 8; ++j)
    dstw[((size_t)tile * 64 + l) * 8 + j] =
        (_Float16)srcw[(size_t)(ks * 32 + q * 8 + j) * J + jt * 16 + m];
}

// ---- merged: binB (blocks<CB) || fused_in_dual (blocks>=CB) ----
union MergedSMem {
  struct { int buf[CAP]; int hist[256]; int sh[256]; int cur[256]; int shb[256]; } b;
  float myl[4][16 * 68];
};

__global__ void __launch_bounds__(256) binB_indual_k(
    const unsigned int* __restrict__ words, const int* __restrict__ bcnt,
    int* __restrict__ off, float* __restrict__ invE, int* __restrict__ csr,
    const float* __restrict__ A, const _Float16* __restrict__ wbuf,
    const float* __restrict__ b_in, const float* __restrict__ b1a,
    const float* __restrict__ b1b, __half* __restrict__ x, __half* __restrict__ h) {
  __shared__ MergedSMem sm;
  if (blockIdx.x < CB) {
    int b = blockIdx.x, t = threadIdx.x;
    int e0 = b << 8;
    int ecnt = min(256, NE - e0);
    int cntb = bcnt[b];
    sm.b.shb[t] = (t < CB) ? bcnt[t] : 0;
    __syncthreads();
    for (int ofs = 1; ofs < 256; ofs <<= 1) {
      int v = (t >= ofs) ? sm.b.shb[t - ofs] : 0;
      __syncthreads();
      sm.b.shb[t] += v;
      __syncthreads();
    }
    int gbase = sm.b.shb[b] - cntb;
    const unsigned int* wp = words + (size_t)b * CAP;
    sm.b.hist[t] = 0;
    __syncthreads();
    for (int i = t; i < cntb; i += 256) atomicAdd(&sm.b.hist[wp[i] >> 24], 1);
    __syncthreads();
    int c = sm.b.hist[t];
    sm.b.sh[t] = c;
    __syncthreads();
    for (int ofs = 1; ofs < 256; ofs <<= 1) {
      int v = (t >= ofs) ? sm.b.sh[t - ofs] : 0;
      __syncthreads();
      sm.b.sh[t] += v;
      __syncthreads();
    }
    int excl = sm.b.sh[t] - c;
    if (t < ecnt) {
      off[e0 + t] = gbase + excl;
      invE[e0 + t] = 1.0f / (float)max(c, 1);
    }
    if (b == CB - 1 && t == 0) off[NE] = NZ;
    sm.b.cur[t] = excl;
    __syncthreads();
    for (int i = t; i < cntb; i += 256) {
      unsigned w = wp[i];
      int s = (int)(w & 0xFFFFFFu);
      int p = atomicAdd(&sm.b.cur[w >> 24], 1);
      if (p < CAP) sm.b.buf[p] = s;
      else csr[gbase + p] = s;  // statistically never
    }
    __syncthreads();
    int lim = min(cntb, CAP);
    for (int i = t; i < lim; i += 256) csr[gbase + i] = sm.b.buf[i];
    return;
  }
  // ---- fused_in_dual branch ----
  int l = threadIdx.x & 63, q = l >> 4, m16 = l & 15, wv = threadIdx.x >> 6;
  int wid = ((blockIdx.x - CB) * 256 + (int)threadIdx.x) >> 6;
  int nw = (MMGRID * 256) >> 6;
  const h8* wip = (const h8*)(wbuf + OFF_IN);
  const h8* wap = (const h8*)(wbuf + OFF_1A);
  const h8* wbp = (const h8*)(wbuf + OFF_1B);
  h8 wi[16], wa[8], wb[8];
#pragma unroll
  for (int f = 0; f < 16; ++f) wi[f] = wip[f * 64 + l];
#pragma unroll
  for (int f = 0; f < 8; ++f) { wa[f] = wap[f * 64 + l]; wb[f] = wbp[f * 64 + l]; }
  float bi[4], ba[4], bb[4];
#pragma unroll
  for (int jt = 0; jt < 4; ++jt) {
    bi[jt] = b_in[jt * 16 + m16]; ba[jt] = b1a[jt * 16 + m16]; bb[jt] = b1b[jt * 16 + m16];
  }
  float* myl = sm.myl[wv];
  for (int t = wid; t < NTILE; t += nw) {
    int rbase = t * 16;
    const float* rp = A + (size_t)(rbase + m16) * 128 + q * 8;
    h8 a0 = ld_a32(rp), a1 = ld_a32(rp + 32), a2 = ld_a32(rp + 64), a3 = ld_a32(rp + 96);
    f4 acc[4];
#pragma unroll
    for (int jt = 0; jt < 4; ++jt) {
      acc[jt] = zero4();
      acc[jt] = MFMA(a0, wi[jt * 4 + 0], acc[jt]);
      acc[jt] = MFMA(a1, wi[jt * 4 + 1], acc[jt]);
      acc[jt] = MFMA(a2, wi[jt * 4 + 2], acc[jt]);
      acc[jt] = MFMA(a3, wi[jt * 4 + 3], acc[jt]);
    }
#pragma unroll
    for (int jt = 0; jt < 4; ++jt)
#pragma unroll
      for (int r = 0; r < 4; ++r) {
        float v = fmaxf(acc[jt][r] + bi[jt], 0.0f);
        x[(size_t)(rbase + q * 4 + r) * 64 + jt * 16 + m16] = __float2half(v);
        myl[(q * 4 + r) * 68 + jt * 16 + m16] = v;
      }
    h8 t0, t1;
    lds_tr(myl, m16, q, t0, t1);
#pragma unroll
    for (int jt = 0; jt < 4; ++jt) {
      acc[jt] = zero4();
      acc[jt] = MFMA(t0, wa[jt * 2 + 0], acc[jt]);
      acc[jt] = MFMA(t1, wa[jt * 2 + 1], acc[jt]);
    }
#pragma unroll
    for (int jt = 0; jt < 4; ++jt)
#pragma unroll
      for (int r = 0; r < 4; ++r)
        myl[(q * 4 + r) * 68 + jt * 16 + m16] = fmaxf(acc[jt][r] + ba[jt], 0.0f);
    lds_tr(myl, m16, q, t0, t1);
#pragma unroll
    for (int jt = 0; jt < 4; ++jt) {
      acc[jt] = zero4();
      acc[jt] = MFMA(t0, wb[jt * 2 + 0], acc[jt]);
      acc[jt] = MFMA(t1, wb[jt * 2 + 1], acc[jt]);
    }
#pragma unroll
    for (int jt = 0; jt < 4; ++jt)
#pragma unroll
      for (int r = 0; r < 4; ++r)
        h[(size_t)(rbase + q * 4 + r) * 64 + jt * 16 + m16] = __float2half(acc[jt][r] + bb[jt]);
  }
}

// ---- pipelined segment-mean gather core (ve_pull only) ----
__device__ __forceinline__ void segmean_pf(const __half* __restrict__ rows,
    const int* __restrict__ idxArr, int lo, int hi, int zrow, float inv,
    __half* __restrict__ outp, int gid, int c) {
  float acc[8];
#pragma unroll
  for (int j = 0; j < 8; ++j) acc[j] = 0.0f;
  int n = hi - lo;
  if (n > 0) {
    int lim = hi - 1;
    int i = lo;
    int j0 = idxArr[i];
    int j1 = idxArr[min(i + 1, lim)]; j1 = (i + 1 <= lim) ? j1 : zrow;
    int j2 = idxArr[min(i + 2, lim)]; j2 = (i + 2 <= lim) ? j2 : zrow;
    int j3 = idxArr[min(i + 3, lim)]; j3 = (i + 3 <= lim) ? j3 : zrow;
    int nb = (n + 3) >> 2;
    for (int b = 0; b < nb; ++b) {
      h8 v0 = *(const h8*)(rows + (size_t)j0 * 64 + c * 8);
      h8 v1 = *(const h8*)(rows + (size_t)j1 * 64 + c * 8);
      h8 v2 = *(const h8*)(rows + (size_t)j2 * 64 + c * 8);
      h8 v3 = *(const h8*)(rows + (size_t)j3 * 64 + c * 8);
      i += 4;
      int n0 = idxArr[min(i, lim)];     n0 = (i     <= lim) ? n0 : zrow;
      int n1 = idxArr[min(i + 1, lim)]; n1 = (i + 1 <= lim) ? n1 : zrow;
      int n2 = idxArr[min(i + 2, lim)]; n2 = (i + 2 <= lim) ? n2 : zrow;
      int n3 = idxArr[min(i + 3, lim)]; n3 = (i + 3 <= lim) ? n3 : zrow;
#pragma unroll
      for (int j = 0; j < 8; ++j)
        acc[j] += ((float)v0[j] + (float)v1[j]) + ((float)v2[j] + (float)v3[j]);
      j0 = n0; j1 = n1; j2 = n2; j3 = n3;
    }
  }
  h8 o;
#pragma unroll
  for (int j = 0; j < 8; ++j) o[j] = (_Float16)(acc[j] * inv);
  *(h8*)(outp + (size_t)gid * 64 + c * 8) = o;
}

// ---- V->E pull: 8-lane group per edge, 128B row reads ----
__global__ void __launch_bounds__(256) ve_pull_k(const __half* __restrict__ h,
    const int* __restrict__ csr, const int* __restrict__ off,
    const float* __restrict__ invE, __half* __restrict__ Xe, int e) {
  int gid = (blockIdx.x * blockDim.x + threadIdx.x) >> 3;
  if (gid >= e) return;
  int c = threadIdx.x & 7;
  segmean_pf(h, csr, off[gid], off[gid + 1], NN, invE[gid], Xe, gid, c);
}

// ---- fused: in-tile zgather + layer-1 catmm_w3 + layer-2 W1 MLP ----
__global__ void __launch_bounds__(256, 3) fused_zcat_dual(const __half* __restrict__ xin,
    const __half* __restrict__ Xe, const __half* __restrict__ x0,
    const int* __restrict__ dstArr, const int* __restrict__ roff,
    const _Float16* __restrict__ wbuf,
    const float* __restrict__ b2, const float* __restrict__ b3,
    const float* __restrict__ b1a, const float* __restrict__ b1b,
    __half* __restrict__ xout, __half* __restrict__ h, int ntiles) {
  __shared__ float lds[4][16 * 68];
  int l = threadIdx.x & 63, q = l >> 4, m16 = l & 15, wv = threadIdx.x >> 6;
  int wid = (blockIdx.x * blockDim.x + threadIdx.x) >> 6;
  int nw = (gridDim.x * blockDim.x) >> 6;
  const h8* w2p = (const h8*)(wbuf + OFF_W2);
  const h8* w3p = (const h8*)(wbuf + OFF_W3);
  const h8* wap = (const h8*)(wbuf + OFF_1A);
  const h8* wbp = (const h8*)(wbuf + OFF_1B);
  h8 w2[16], w3[8], wa[8], wb[8];
#pragma unroll
  for (int f = 0; f < 16; ++f) w2[f] = w2p[f * 64 + l];
#pragma unroll
  for (int f = 0; f < 8; ++f) { w3[f] = w3p[f * 64 + l]; wa[f] = wap[f * 64 + l]; wb[f] = wbp[f * 64 + l]; }
  float bv2[4], bv3[4], ba[4], bb[4];
#pragma unroll
  for (int jt = 0; jt < 4; ++jt) {
    bv2[jt] = b2[jt * 16 + m16]; bv3[jt] = b3[jt * 16 + m16];
    ba[jt] = b1a[jt * 16 + m16]; bb[jt] = b1b[jt * 16 + m16];
  }
  float* myl = lds[wv];
  for (int t = wid; t < ntiles; t += nw) {
    int rbase = t * 16;
    // gather z tile into LDS (fp32), then consume via lds_tr
    tile_zgather(Xe, dstArr, roff, rbase, l, myl);
    h8 az0, az1;
    lds_tr(myl, m16, q, az0, az1);
    const __half* rp = xin + (size_t)(rbase + m16) * 64 + q * 8;
    h8 a0 = *(const h8*)rp, a1 = *(const h8*)(rp + 32);
    f4 acc[4];
#pragma unroll
    for (int jt = 0; jt < 4; ++jt) {
      acc[jt] = zero4();
      acc[jt] = MFMA(a0,  w2[jt * 4 + 0], acc[jt]);
      acc[jt] = MFMA(a1,  w2[jt * 4 + 1], acc[jt]);
      acc[jt] = MFMA(az0, w2[jt * 4 + 2], acc[jt]);
      acc[jt] = MFMA(az1, w2[jt * 4 + 3], acc[jt]);
    }
#pragma unroll
    for (int r = 0; r < 4; ++r) {
      int row = rbase + q * 4 + r;
      float msk = (roff[row + 1] > roff[row]) ? 0.5f : 0.0f;
#pragma unroll
      for (int jt = 0; jt < 4; ++jt) {
        float val = acc[jt][r] + bv2[jt];
        float x0v = __half2float(x0[(size_t)row * 64 + jt * 16 + m16]);
        myl[(q * 4 + r) * 68 + jt * 16 + m16] = fmaf(msk, val, 0.5f * x0v);
      }
    }
    h8 t0, t1;
    lds_tr(myl, m16, q, t0, t1);
#pragma unroll
    for (int jt = 0; jt < 4; ++jt) {
      acc[jt] = zero4();
      acc[jt] = MFMA(t0, w3[jt * 2 + 0], acc[jt]);
      acc[jt] = MFMA(t1, w3[jt * 2 + 1], acc[jt]);
    }
#pragma unroll
    for (int jt = 0; jt < 4; ++jt)
#pragma unroll
      for (int r = 0; r < 4; ++r) {
        float v = fmaxf(acc[jt][r] + bv3[jt], 0.0f);
        xout[(size_t)(rbase + q * 4 + r) * 64 + jt * 16 + m16] = __float2half(v);
        myl[(q * 4 + r) * 68 + jt * 16 + m16] = v;
      }
    lds_tr(myl, m16, q, t0, t1);
#pragma unroll
    for (int jt = 0; jt < 4; ++jt) {
      acc[jt] = zero4();
      acc[jt] = MFMA(t0, wa[jt * 2 + 0], acc[jt]);
      acc[jt] = MFMA(t1, wa[jt * 2 + 1], acc[jt]);
    }
#pragma unroll
    for (int jt = 0; jt < 4; ++jt)
#pragma unroll
      for (int r = 0; r < 4; ++r)
        myl[(q * 4 + r) * 68 + jt * 16 + m16] = fmaxf(acc[jt][r] + ba[jt], 0.0f);
    lds_tr(myl, m16, q, t0, t1);
#pragma unroll
    for (int jt = 0; jt < 4; ++jt) {
      acc[jt] = zero4();
      acc[jt] = MFMA(t0, wb[jt * 2 + 0], acc[jt]);
      acc[jt] = MFMA(t1, wb[jt * 2 + 1], acc[jt]);
    }
#pragma unroll
    for (int jt = 0; jt < 4; ++jt)
#pragma unroll
      for (int r = 0; r < 4; ++r)
        h[(size_t)(rbase + q * 4 + r) * 64 + jt * 16 + m16] = __float2half(acc[jt][r] + bb[jt]);
  }
}

// ---- fused: in-tile zgather + layer-2 catmm_w3 + classifier ----
__global__ void __launch_bounds__(256, 3) fused_zcat_cls(const __half* __restrict__ xin,
    const __half* __restrict__ Xe, const __half* __restrict__ x0,
    const int* __restrict__ dstArr, const int* __restrict__ roff,
    const _Float16* __restrict__ wbuf,
    const float* __restrict__ b2, const float* __restrict__ b3,
    const float* __restrict__ bc1, const float* __restrict__ bc2,
    __half* __restrict__ out, int ntiles) {
  __shared__ float lds[4][16 * 68];
  int l = threadIdx.x & 63, q = l >> 4, m16 = l & 15, wv = threadIdx.x >> 6;
  int wid = (blockIdx.x * blockDim.x + threadIdx.x) >> 6;
  int nw = (gridDim.x * blockDim.x) >> 6;
  const h8* w2p = (const h8*)(wbuf + OFF_W2);
  const h8* w3p = (const h8*)(wbuf + OFF_W3);
  const h8* wc1p = (const h8*)(wbuf + OFF_C1);
  const h8* wc2p = (const h8*)(wbuf + OFF_C2);
  h8 w2[16], w3[8], wc1[8], wc2[4];
#pragma unroll
  for (int f = 0; f < 16; ++f) w2[f] = w2p[f * 64 + l];
#pragma unroll
  for (int f = 0; f < 8; ++f) { w3[f] = w3p[f * 64 + l]; wc1[f] = wc1p[f * 64 + l]; }
#pragma unroll
  for (int f = 0; f < 4; ++f) wc2[f] = wc2p[f * 64 + l];
  float bv2[4], bv3[4], bv1[4], bvo[2];
#pragma unroll
  for (int jt = 0; jt < 4; ++jt) {
    bv2[jt] = b2[jt * 16 + m16]; bv3[jt] = b3[jt * 16 + m16]; bv1[jt] = bc1[jt * 16 + m16];
  }
#pragma unroll
  for (int jt = 0; jt < 2; ++jt) bvo[jt] = bc2[jt * 16 + m16];
  float* myl = lds[wv];
  for (int t = wid; t < ntiles; t += nw) {
    int rbase = t * 16;
    tile_zgather(Xe, dstArr, roff, rbase, l, myl);
    h8 az0, az1;
    lds_tr(myl, m16, q, az0, az1);
    const __half* rp = xin + (size_t)(rbase + m16) * 64 + q * 8;
    h8 a0 = *(const h8*)rp, a1 = *(const h8*)(rp + 32);
    f4 acc[4];
#pragma unroll
    for (int jt = 0; jt < 4; ++jt) {
      acc[jt] = zero4();
      acc[jt] = MFMA(a0,  w2[jt * 4 + 0], acc[jt]);
      acc[jt] = MFMA(a1,  w2[jt * 4 + 1], acc[jt]);
      acc[jt] = MFMA(az0, w2[jt * 4 + 2], acc[jt]);
      acc[jt] = MFMA(az1, w2[jt * 4 + 3], acc[jt]);
    }
#pragma unroll
    for (int r = 0; r < 4; ++r) {
      int row = rbase + q * 4 + r;
      float msk = (roff[row + 1] > roff[row]) ? 0.5f : 0.0f;
#pragma unroll
      for (int jt = 0; jt < 4; ++jt) {
        float val = acc[jt][r] + bv2[jt];
        float x0v = __half2float(x0[(size_t)row * 64 + jt * 16 + m16]);
        myl[(q * 4 + r) * 68 + jt * 16 + m16] = fmaf(msk, val, 0.5f * x0v);
      }
    }
    h8 t0, t1;
    lds_tr(myl, m16, q, t0, t1);
#pragma unroll
    for (int jt = 0; jt < 4; ++jt) {
      acc[jt] = zero4();
      acc[jt] = MFMA(t0, w3[jt * 2 + 0], acc[jt]);
      acc[jt] = MFMA(t1, w3[jt * 2 + 1], acc[jt]);
    }
#pragma unroll
    for (int jt = 0; jt < 4; ++jt)
#pragma unroll
      for (int r = 0; r < 4; ++r)
        myl[(q * 4 + r) * 68 + jt * 16 + m16] = fmaxf(acc[jt][r] + bv3[jt], 0.0f);
    lds_tr(myl, m16, q, t0, t1);
#pragma unroll
    for (int jt = 0; jt < 4; ++jt) {
      acc[jt] = zero4();
      acc[jt] = MFMA(t0, wc1[jt * 2 + 0], acc[jt]);
      acc[jt] = MFMA(t1, wc1[jt * 2 + 1], acc[jt]);
    }
#pragma unroll
    for (int jt = 0; jt < 4; ++jt)
#pragma unroll
      for (int r = 0; r < 4; ++r)
        myl[(q * 4 + r) * 68 + jt * 16 + m16] = fmaxf(acc[jt][r] + bv1[jt], 0.0f);
    lds_tr(myl, m16, q, t0, t1);
    f4 o[2];
#pragma unroll
    for (int jt = 0; jt < 2; ++jt) {
      o[jt] = zero4();
      o[jt] = MFMA(t0, wc2[jt * 2 + 0], o[jt]);
      o[jt] = MFMA(t1, wc2[jt * 2 + 1], o[jt]);
    }
#pragma unroll
    for (int jt = 0; jt < 2; ++jt)
#pragma unroll
      for (int r = 0; r < 4; ++r)
        out[(size_t)(rbase + q * 4 + r) * 32 + jt * 16 + m16] =
            __float2half(o[jt][r] + bvo[jt]);
  }
}

// ---- per-graph mean readout; fp16 input ----
__global__ void __launch_bounds__(256) readout_k(const __half* __restrict__ xc,
    const int* __restrict__ batch, int n, float* __restrict__ out) {
  __shared__ float part[8][32];
  int g = blockIdx.x;
  int lo = lbound(batch, n, g);
  int hi = lbound(batch, n, g + 1);
  int j = threadIdx.x & 31, r = threadIdx.x >> 5;
  float acc = 0.0f;
  for (int i = lo + r; i < hi; i += 8) acc += __half2float(xc[(size_t)i * 32 + j]);
  part[r][j] = acc;
  __syncthreads();
  if (threadIdx.x < 32) {
    float s = 0.0f;
#pragma unroll
    for (int rr = 0; rr < 8; ++rr) s += part[rr][j];
    out[g * 32 + j] = (hi > lo) ? s / (float)(hi - lo) : 0.0f;
  }
}

extern "C" void kernel_launch(void* const* d_in, const int* in_sizes, int n_in,
                              void* d_out, int out_size, void* d_ws, size_t ws_size,
                              hipStream_t stream) {
  const float* X    = (const float*)d_in[0];
  const int*   src  = (const int*)d_in[1];
  const int*   dst  = (const int*)d_in[2];
  const int*   batch= (const int*)d_in[3];
  const float* W_in = (const float*)d_in[4];
  const float* b_in = (const float*)d_in[5];
  const float* W1a  = (const float*)d_in[6];
  const float* b1a  = (const float*)d_in[7];
  const float* W1b  = (const float*)d_in[8];
  const float* b1b  = (const float*)d_in[9];
  const float* W2   = (const float*)d_in[10];
  const float* b2   = (const float*)d_in[11];
  const float* W3   = (const float*)d_in[12];
  const float* b3   = (const float*)d_in[13];
  const float* Wc1  = (const float*)d_in[14];
  const float* bc1  = (const float*)d_in[15];
  const float* Wc2  = (const float*)d_in[16];
  const float* bc2  = (const float*)d_in[17];
  float* out = (float*)d_out;

  // workspace layout (~57 MB)
  float* p  = (float*)d_ws;
  __half* xA = (__half*)p; p += (size_t)NN * 32;       // x0 / layer-1 x
  __half* xB = (__half*)p; p += (size_t)NN * 32;       // layer-1 out / layer-2 x
  __half* hz = (__half*)p; p += (size_t)NN * 32 + 32;  // h (+zero row NN); logits at end
  __half* Xe = (__half*)p; p += (size_t)NE * 32 + 32;  // Xe
  float* invE = p; p += NE;
  _Float16* wbuf = (_Float16*)p; p += WBUF_HALVES / 2 + 16;
  int* q     = (int*)p;
  int* off   = q; q += NE + 1;
  int* bcnt  = q; q += 256;
  int* roff  = q; q += NN + 1;
  int* csr   = q; q += NZ;        // 5.12 MB
  unsigned int* words = (unsigned int*)q; q += CB * CAP;  // 6.4 MB
  __half* h = hz;
  __half* outc = hz;         // alias: layer-2 h dead after 2nd ve_pull

  // roff + weight prep + dummy-row zero
  prep_misc_k<<<NBLK_ROW + 69, 256, 0, stream>>>(src, roff, bcnt, NN, NZ,
      W_in, W1a, W1b, W2, W3, Wc1, Wc2, wbuf, hz);
  binA_k<<<NBLK_A, 256, 0, stream>>>(src, dst, bcnt, words);

  // binB || layer-1 front half (x=x0=xA, h) in one dispatch
  binB_indual_k<<<CB + MMGRID, 256, 0, stream>>>(words, bcnt, off, invE, csr,
      X, wbuf, b_in, b1a, b1b, xA, h);

  ve_pull_k<<<(NE * 8 + 255) / 256, 256, 0, stream>>>(h, csr, off, invE, Xe, NE);

  // [zgather + layer-1 cat+W3 + layer-2 W1 MLP] in one kernel
  fused_zcat_dual<<<CATGRID, 256, 0, stream>>>(xA, Xe, xA, dst, roff, wbuf,
                                               b2, b3, b1a, b1b, xB, h, NTILE);

  ve_pull_k<<<(NE * 8 + 255) / 256, 256, 0, stream>>>(h, csr, off, invE, Xe, NE);

  // [zgather + layer-2 cat+W3 + classifier]: logits -> outc (hz region)
  fused_zcat_cls<<<CATGRID, 256, 0, stream>>>(xB, Xe, xA, dst, roff, wbuf,
                                              b2, b3, bc1, bc2, outc, NTILE);
  readout_k<<<NG, 256, 0, stream>>>(outc, batch, NN, out);
}

// Round 8
// 322.341 us; speedup vs baseline: 1.4015x; 1.3387x over previous
//
#include <hip/hip_runtime.h>
#include <hip/hip_fp16.h>

// EquivSetGNN forward, MI355X.
// R21: revert R20 (fused zgather+MM = 110us: gather lost its TLP at MM
// occupancy; gathers and MM want opposite operating points -> separate
// kernels). Base = R18 (303us). Deltas:
//  (1) two-tile interleave in the 3 MFMA kernels: wave owns tiles t and
//      t+3125, phases written over an unrolled p-pair -> 2 independent
//      latency chains/wave (cat kernels were 1.8 TB/s = latency-bound),
//      grid 782 = 3128 waves x exactly 2 tiles, no tail. LDS 2 slices/wave.
//  (2) prep_misc + binA merged into one dispatch (bcnt zeroed by
//      hipMemsetAsync; stream-ordered, graph-capture-safe).

constexpr int NN = 100000;   // nodes
constexpr int NE = 50000;    // hyperedges
constexpr int NZ = 1280000;  // incidences
constexpr int NG = 256;      // graphs
constexpr int NTILE = NN / 16;  // 6250 row-tiles of 16
constexpr int HALF = NTILE / 2; // 3125
constexpr int CB = 196;         // coarse buckets
constexpr int CAP = 8192;       // bucket region capacity (words)
constexpr int CHUNK = 4000;
constexpr int NBLK_A = NZ / CHUNK;          // 320
constexpr int NBLK_ROW = (NZ + 255) / 256;  // 5000
constexpr int MMGRID = 782;                 // 3128 waves = HALF coverage

typedef _Float16 h8 __attribute__((ext_vector_type(8)));
typedef float f4 __attribute__((ext_vector_type(4)));

constexpr int OFF_IN  = 0;
constexpr int OFF_1A  = 8192;
constexpr int OFF_1B  = 12288;
constexpr int OFF_W2  = 16384;
constexpr int OFF_W3  = 24576;
constexpr int OFF_C1  = 28672;
constexpr int OFF_C2  = 32768;
constexpr int WBUF_HALVES = 34816;

__device__ __forceinline__ int lbound(const int* a, int n, int v) {
  int lo = 0, hi = n;
  while (lo < hi) { int m = (lo + hi) >> 1; if (a[m] < v) lo = m + 1; else hi = m; }
  return lo;
}

__device__ __forceinline__ f4 zero4() { f4 z; z[0]=0.f; z[1]=0.f; z[2]=0.f; z[3]=0.f; return z; }

__device__ __forceinline__ h8 ld_a32(const float* p) {
  const f4* v = (const f4*)p;
  f4 lo = v[0], hi = v[1];
  h8 r;
  r[0]=(_Float16)lo[0]; r[1]=(_Float16)lo[1]; r[2]=(_Float16)lo[2]; r[3]=(_Float16)lo[3];
  r[4]=(_Float16)hi[0]; r[5]=(_Float16)hi[1]; r[6]=(_Float16)hi[2]; r[7]=(_Float16)hi[3];
  return r;
}

// LDS transpose read: lane gets row m16, cols q*8..q*8+7 (t0) and +32 (t1),
// via four aligned f4 vector loads (2-way bank alias only -> conflict-free).
__device__ __forceinline__ void lds_tr(const float* __restrict__ myl, int m16, int q,
                                       h8& t0, h8& t1) {
  const f4* rp = (const f4*)(myl + m16 * 68);
  f4 u0 = rp[q * 2], u1 = rp[q * 2 + 1];
  f4 u2 = rp[8 + q * 2], u3 = rp[8 + q * 2 + 1];
#pragma unroll
  for (int j = 0; j < 4; ++j) {
    t0[j] = (_Float16)u0[j]; t0[j + 4] = (_Float16)u1[j];
    t1[j] = (_Float16)u2[j]; t1[j + 4] = (_Float16)u3[j];
  }
}

#define MFMA(a, b, c) __builtin_amdgcn_mfma_f32_16x16x32_f16((a), (b), (c), 0, 0, 0)

// ---- merged: roff | weight prep | dummy-row zero | binA chunks ----
// bcnt must be zeroed before launch (hipMemsetAsync).
__global__ void __launch_bounds__(256) prep_binA_k(const int* __restrict__ src,
    const int* __restrict__ dst, int* __restrict__ roff, int* __restrict__ bcnt,
    unsigned int* __restrict__ words, int n, int nnz,
    const float* __restrict__ W_in, const float* __restrict__ W1a,
    const float* __restrict__ W1b, const float* __restrict__ W2,
    const float* __restrict__ W3,  const float* __restrict__ Wc1,
    const float* __restrict__ Wc2, _Float16* __restrict__ wbuf,
    __half* __restrict__ hz, __half* __restrict__ Xe) {
  __shared__ int cnt[CB];
  __shared__ int base[CB];
  int blk = blockIdx.x;
  if (blk < NBLK_ROW) {
    int i = blk * 256 + threadIdx.x;
    if (i >= nnz) return;
    int s = src[i];
    int prev = (i == 0) ? -1 : src[i - 1];
    for (int v = prev + 1; v <= s; ++v) roff[v] = i;
    if (i == nnz - 1) {
      for (int v = s + 1; v <= n; ++v) roff[v] = nnz;
    }
    return;
  }
  int b = blk - NBLK_ROW;
  if (b < 68) {
    int l = threadIdx.x;
    if (l >= 64) return;
    const float* srcw; int K, J; _Float16* dstw; int tile;
    if      (b < 16) { srcw = W_in; K = 128; J = 64; dstw = wbuf + OFF_IN; tile = b; }
    else if (b < 24) { srcw = W1a;  K = 64;  J = 64; dstw = wbuf + OFF_1A; tile = b - 16; }
    else if (b < 32) { srcw = W1b;  K = 64;  J = 64; dstw = wbuf + OFF_1B; tile = b - 24; }
    else if (b < 48) { srcw = W2;   K = 128; J = 64; dstw = wbuf + OFF_W2; tile = b - 32; }
    else if (b < 56) { srcw = W3;   K = 64;  J = 64; dstw = wbuf + OFF_W3; tile = b - 48; }
    else if (b < 64) { srcw = Wc1;  K = 64;  J = 64; dstw = wbuf + OFF_C1; tile = b - 56; }
    else             { srcw = Wc2;  K = 64;  J = 32; dstw = wbuf + OFF_C2; tile = b - 64; }
    int KS = K / 32;
    int jt = tile / KS, ks = tile % KS;
    int q = l >> 4, m = l & 15;
#pragma unroll
    for (int j = 0; j < 8; ++j)
      dstw[((size_t)tile * 64 + l) * 8 + j] =
          (_Float16)srcw[(size_t)(ks * 32 + q * 8 + j) * J + jt * 16 + m];
    return;
  }
  if (b == 68) {
    int t = threadIdx.x;
    if (t < 32) ((float*)(hz + (size_t)NN * 64))[t] = 0.0f;        // h dummy row NN
    else if (t < 64) ((float*)(Xe + (size_t)NE * 64))[t - 32] = 0.0f;  // Xe dummy row NE
    return;
  }
  // ---- binA chunk ----
  int c = b - 69;
  int t = threadIdx.x;
  int start = c * CHUNK;
  for (int i = t; i < CB; i += 256) cnt[i] = 0;
  __syncthreads();
  for (int i = start + t; i < start + CHUNK; i += 256)
    atomicAdd(&cnt[dst[i] >> 8], 1);
  __syncthreads();
  for (int i = t; i < CB; i += 256) base[i] = atomicAdd(&bcnt[i], cnt[i]);
  __syncthreads();
  for (int i = t; i < CB; i += 256) cnt[i] = 0;  // reuse as cursor
  __syncthreads();
  for (int i = start + t; i < start + CHUNK; i += 256) {
    int d = dst[i];
    int bb2 = d >> 8;
    int p = base[bb2] + atomicAdd(&cnt[bb2], 1);
    words[(size_t)bb2 * CAP + p] = (unsigned)src[i] | ((unsigned)(d & 255) << 24);
  }
}

// ---- merged: binB (blocks<CB) || fused_in_dual (blocks>=CB, 2-tile ILP) ----
union MergedSMem {
  struct { int buf[CAP]; int hist[256]; int sh[256]; int cur[256]; int shb[256]; } b;
  float myl[4][2][16 * 68];
};

__global__ void __launch_bounds__(256) binB_indual_k(
    const unsigned int* __restrict__ words, const int* __restrict__ bcnt,
    int* __restrict__ off, float* __restrict__ invE, int* __restrict__ csr,
    const float* __restrict__ A, const _Float16* __restrict__ wbuf,
    const float* __restrict__ b_in, const float* __restrict__ b1a,
    const float* __restrict__ b1b, __half* __restrict__ x, __half* __restrict__ h) {
  __shared__ MergedSMem sm;
  if (blockIdx.x < CB) {
    int b = blockIdx.x, t = threadIdx.x;
    int e0 = b << 8;
    int ecnt = min(256, NE - e0);
    int cntb = bcnt[b];
    sm.b.shb[t] = (t < CB) ? bcnt[t] : 0;
    __syncthreads();
    for (int ofs = 1; ofs < 256; ofs <<= 1) {
      int v = (t >= ofs) ? sm.b.shb[t - ofs] : 0;
      __syncthreads();
      sm.b.shb[t] += v;
      __syncthreads();
    }
    int gbase = sm.b.shb[b] - cntb;
    const unsigned int* wp = words + (size_t)b * CAP;
    sm.b.hist[t] = 0;
    __syncthreads();
    for (int i = t; i < cntb; i += 256) atomicAdd(&sm.b.hist[wp[i] >> 24], 1);
    __syncthreads();
    int c = sm.b.hist[t];
    sm.b.sh[t] = c;
    __syncthreads();
    for (int ofs = 1; ofs < 256; ofs <<= 1) {
      int v = (t >= ofs) ? sm.b.sh[t - ofs] : 0;
      __syncthreads();
      sm.b.sh[t] += v;
      __syncthreads();
    }
    int excl = sm.b.sh[t] - c;
    if (t < ecnt) {
      off[e0 + t] = gbase + excl;
      invE[e0 + t] = 1.0f / (float)max(c, 1);
    }
    if (b == CB - 1 && t == 0) off[NE] = NZ;
    sm.b.cur[t] = excl;
    __syncthreads();
    for (int i = t; i < cntb; i += 256) {
      unsigned w = wp[i];
      int s = (int)(w & 0xFFFFFFu);
      int p = atomicAdd(&sm.b.cur[w >> 24], 1);
      if (p < CAP) sm.b.buf[p] = s;
      else csr[gbase + p] = s;  // statistically never
    }
    __syncthreads();
    int lim = min(cntb, CAP);
    for (int i = t; i < lim; i += 256) csr[gbase + i] = sm.b.buf[i];
    return;
  }
  // ---- fused_in_dual branch: 2-tile interleave ----
  int l = threadIdx.x & 63, q = l >> 4, m16 = l & 15, wv = threadIdx.x >> 6;
  int wid = ((blockIdx.x - CB) * 256 + (int)threadIdx.x) >> 6;
  int nw = (MMGRID * 256) >> 6;  // 3128
  const h8* wip = (const h8*)(wbuf + OFF_IN);
  const h8* wap = (const h8*)(wbuf + OFF_1A);
  const h8* wbp = (const h8*)(wbuf + OFF_1B);
  h8 wi[16], wa[8], wb[8];
#pragma unroll
  for (int f = 0; f < 16; ++f) wi[f] = wip[f * 64 + l];
#pragma unroll
  for (int f = 0; f < 8; ++f) { wa[f] = wap[f * 64 + l]; wb[f] = wbp[f * 64 + l]; }
  float bi[4], ba[4], bb[4];
#pragma unroll
  for (int jt = 0; jt < 4; ++jt) {
    bi[jt] = b_in[jt * 16 + m16]; ba[jt] = b1a[jt * 16 + m16]; bb[jt] = b1b[jt * 16 + m16];
  }
  for (int t = wid; t < HALF; t += nw) {
    int rb[2] = {t * 16, (t + HALF) * 16};
    h8 a0[2], a1[2], a2[2], a3[2];
#pragma unroll
    for (int p = 0; p < 2; ++p) {
      const float* rp = A + (size_t)(rb[p] + m16) * 128 + q * 8;
      a0[p] = ld_a32(rp); a1[p] = ld_a32(rp + 32);
      a2[p] = ld_a32(rp + 64); a3[p] = ld_a32(rp + 96);
    }
    f4 acc[2][4];
#pragma unroll
    for (int p = 0; p < 2; ++p)
#pragma unroll
      for (int jt = 0; jt < 4; ++jt) {
        acc[p][jt] = zero4();
        acc[p][jt] = MFMA(a0[p], wi[jt * 4 + 0], acc[p][jt]);
        acc[p][jt] = MFMA(a1[p], wi[jt * 4 + 1], acc[p][jt]);
        acc[p][jt] = MFMA(a2[p], wi[jt * 4 + 2], acc[p][jt]);
        acc[p][jt] = MFMA(a3[p], wi[jt * 4 + 3], acc[p][jt]);
      }
#pragma unroll
    for (int p = 0; p < 2; ++p) {
      float* myl = sm.myl[wv][p];
#pragma unroll
      for (int jt = 0; jt < 4; ++jt)
#pragma unroll
        for (int r = 0; r < 4; ++r) {
          float v = fmaxf(acc[p][jt][r] + bi[jt], 0.0f);
          x[(size_t)(rb[p] + q * 4 + r) * 64 + jt * 16 + m16] = __float2half(v);
          myl[(q * 4 + r) * 68 + jt * 16 + m16] = v;
        }
    }
    h8 t0[2], t1[2];
#pragma unroll
    for (int p = 0; p < 2; ++p) lds_tr(sm.myl[wv][p], m16, q, t0[p], t1[p]);
#pragma unroll
    for (int p = 0; p < 2; ++p)
#pragma unroll
      for (int jt = 0; jt < 4; ++jt) {
        acc[p][jt] = zero4();
        acc[p][jt] = MFMA(t0[p], wa[jt * 2 + 0], acc[p][jt]);
        acc[p][jt] = MFMA(t1[p], wa[jt * 2 + 1], acc[p][jt]);
      }
#pragma unroll
    for (int p = 0; p < 2; ++p) {
      float* myl = sm.myl[wv][p];
#pragma unroll
      for (int jt = 0; jt < 4; ++jt)
#pragma unroll
        for (int r = 0; r < 4; ++r)
          myl[(q * 4 + r) * 68 + jt * 16 + m16] = fmaxf(acc[p][jt][r] + ba[jt], 0.0f);
    }
#pragma unroll
    for (int p = 0; p < 2; ++p) lds_tr(sm.myl[wv][p], m16, q, t0[p], t1[p]);
#pragma unroll
    for (int p = 0; p < 2; ++p)
#pragma unroll
      for (int jt = 0; jt < 4; ++jt) {
        acc[p][jt] = zero4();
        acc[p][jt] = MFMA(t0[p], wb[jt * 2 + 0], acc[p][jt]);
        acc[p][jt] = MFMA(t1[p], wb[jt * 2 + 1], acc[p][jt]);
      }
#pragma unroll
    for (int p = 0; p < 2; ++p)
#pragma unroll
      for (int jt = 0; jt < 4; ++jt)
#pragma unroll
        for (int r = 0; r < 4; ++r)
          h[(size_t)(rb[p] + q * 4 + r) * 64 + jt * 16 + m16] =
              __float2half(acc[p][jt][r] + bb[jt]);
  }
}

// ---- pipelined segment-mean gather core ----
__device__ __forceinline__ void segmean_pf(const __half* __restrict__ rows,
    const int* __restrict__ idxArr, int lo, int hi, int zrow, float inv,
    __half* __restrict__ outp, int gid, int c) {
  float acc[8];
#pragma unroll
  for (int j = 0; j < 8; ++j) acc[j] = 0.0f;
  int n = hi - lo;
  if (n > 0) {
    int lim = hi - 1;
    int i = lo;
    int j0 = idxArr[i];
    int j1 = idxArr[min(i + 1, lim)]; j1 = (i + 1 <= lim) ? j1 : zrow;
    int j2 = idxArr[min(i + 2, lim)]; j2 = (i + 2 <= lim) ? j2 : zrow;
    int j3 = idxArr[min(i + 3, lim)]; j3 = (i + 3 <= lim) ? j3 : zrow;
    int nb = (n + 3) >> 2;
    for (int b = 0; b < nb; ++b) {
      h8 v0 = *(const h8*)(rows + (size_t)j0 * 64 + c * 8);
      h8 v1 = *(const h8*)(rows + (size_t)j1 * 64 + c * 8);
      h8 v2 = *(const h8*)(rows + (size_t)j2 * 64 + c * 8);
      h8 v3 = *(const h8*)(rows + (size_t)j3 * 64 + c * 8);
      i += 4;
      int n0 = idxArr[min(i, lim)];     n0 = (i     <= lim) ? n0 : zrow;
      int n1 = idxArr[min(i + 1, lim)]; n1 = (i + 1 <= lim) ? n1 : zrow;
      int n2 = idxArr[min(i + 2, lim)]; n2 = (i + 2 <= lim) ? n2 : zrow;
      int n3 = idxArr[min(i + 3, lim)]; n3 = (i + 3 <= lim) ? n3 : zrow;
#pragma unroll
      for (int j = 0; j < 8; ++j)
        acc[j] += ((float)v0[j] + (float)v1[j]) + ((float)v2[j] + (float)v3[j]);
      j0 = n0; j1 = n1; j2 = n2; j3 = n3;
    }
  }
  h8 o;
#pragma unroll
  for (int j = 0; j < 8; ++j) o[j] = (_Float16)(acc[j] * inv);
  *(h8*)(outp + (size_t)gid * 64 + c * 8) = o;
}

// ---- V->E pull: 8-lane group per edge, 128B row reads ----
__global__ void __launch_bounds__(256) ve_pull_k(const __half* __restrict__ h,
    const int* __restrict__ csr, const int* __restrict__ off,
    const float* __restrict__ invE, __half* __restrict__ Xe, int e) {
  int gid = (blockIdx.x * blockDim.x + threadIdx.x) >> 3;
  if (gid >= e) return;
  int c = threadIdx.x & 7;
  segmean_pf(h, csr, off[gid], off[gid + 1], NN, invE[gid], Xe, gid, c);
}

// ---- E->V pull: 8-lane group per node ----
__global__ void __launch_bounds__(256) zgather_k(const __half* __restrict__ Xe,
    const int* __restrict__ dstArr, const int* __restrict__ roff,
    __half* __restrict__ z, int n) {
  int gid = (blockIdx.x * blockDim.x + threadIdx.x) >> 3;
  if (gid >= n) return;
  int c = threadIdx.x & 7;
  int lo = roff[gid], hi = roff[gid + 1];
  float inv = (hi > lo) ? 1.0f / (float)(hi - lo) : 0.0f;
  segmean_pf(Xe, dstArr, lo, hi, NE, inv, z, gid, c);
}

// ---- fused: layer-1 catmm_w3 + layer-2 W1 MLP, 2-tile interleave ----
__global__ void __launch_bounds__(256) fused_cat_dual(const __half* xin,
    const __half* z, const __half* x0,
    const int* __restrict__ roff, const _Float16* __restrict__ wbuf,
    const float* __restrict__ b2, const float* __restrict__ b3,
    const float* __restrict__ b1a, const float* __restrict__ b1b,
    __half* __restrict__ xout, __half* h) {
  __shared__ float lds[4][2][16 * 68];
  int l = threadIdx.x & 63, q = l >> 4, m16 = l & 15, wv = threadIdx.x >> 6;
  int wid = (blockIdx.x * blockDim.x + threadIdx.x) >> 6;
  int nw = (gridDim.x * blockDim.x) >> 6;
  const h8* w2p = (const h8*)(wbuf + OFF_W2);
  const h8* w3p = (const h8*)(wbuf + OFF_W3);
  const h8* wap = (const h8*)(wbuf + OFF_1A);
  const h8* wbp = (const h8*)(wbuf + OFF_1B);
  h8 w2[16], w3[8], wa[8], wb[8];
#pragma unroll
  for (int f = 0; f < 16; ++f) w2[f] = w2p[f * 64 + l];
#pragma unroll
  for (int f = 0; f < 8; ++f) { w3[f] = w3p[f * 64 + l]; wa[f] = wap[f * 64 + l]; wb[f] = wbp[f * 64 + l]; }
  float bv2[4], bv3[4], ba[4], bb[4];
#pragma unroll
  for (int jt = 0; jt < 4; ++jt) {
    bv2[jt] = b2[jt * 16 + m16]; bv3[jt] = b3[jt * 16 + m16];
    ba[jt] = b1a[jt * 16 + m16]; bb[jt] = b1b[jt * 16 + m16];
  }
  for (int t = wid; t < HALF; t += nw) {
    int rb[2] = {t * 16, (t + HALF) * 16};
    h8 a0[2], a1[2], az0[2], az1[2];
#pragma unroll
    for (int p = 0; p < 2; ++p) {
      const __half* rp = xin + (size_t)(rb[p] + m16) * 64 + q * 8;
      a0[p] = *(const h8*)rp; a1[p] = *(const h8*)(rp + 32);
      const __half* zr = z + (size_t)(rb[p] + m16) * 64;
      az0[p] = *(const h8*)(zr + q * 8); az1[p] = *(const h8*)(zr + 32 + q * 8);
    }
    f4 acc[2][4];
#pragma unroll
    for (int p = 0; p < 2; ++p)
#pragma unroll
      for (int jt = 0; jt < 4; ++jt) {
        acc[p][jt] = zero4();
        acc[p][jt] = MFMA(a0[p],  w2[jt * 4 + 0], acc[p][jt]);
        acc[p][jt] = MFMA(a1[p],  w2[jt * 4 + 1], acc[p][jt]);
        acc[p][jt] = MFMA(az0[p], w2[jt * 4 + 2], acc[p][jt]);
        acc[p][jt] = MFMA(az1[p], w2[jt * 4 + 3], acc[p][jt]);
      }
#pragma unroll
    for (int p = 0; p < 2; ++p) {
      float* myl = lds[wv][p];
#pragma unroll
      for (int r = 0; r < 4; ++r) {
        int row = rb[p] + q * 4 + r;
        float msk = (roff[row + 1] > roff[row]) ? 0.5f : 0.0f;
#pragma unroll
        for (int jt = 0; jt < 4; ++jt) {
          float val = acc[p][jt][r] + bv2[jt];
          float x0v = __half2float(x0[(size_t)row * 64 + jt * 16 + m16]);
          myl[(q * 4 + r) * 68 + jt * 16 + m16] = fmaf(msk, val, 0.5f * x0v);
        }
      }
    }
    h8 t0[2], t1[2];
#pragma unroll
    for (int p = 0; p < 2; ++p) lds_tr(lds[wv][p], m16, q, t0[p], t1[p]);
#pragma unroll
    for (int p = 0; p < 2; ++p)
#pragma unroll
      for (int jt = 0; jt < 4; ++jt) {
        acc[p][jt] = zero4();
        acc[p][jt] = MFMA(t0[p], w3[jt * 2 + 0], acc[p][jt]);
        acc[p][jt] = MFMA(t1[p], w3[jt * 2 + 1], acc[p][jt]);
      }
#pragma unroll
    for (int p = 0; p < 2; ++p) {
      float* myl = lds[wv][p];
#pragma unroll
      for (int jt = 0; jt < 4; ++jt)
#pragma unroll
        for (int r = 0; r < 4; ++r) {
          float v = fmaxf(acc[p][jt][r] + bv3[jt], 0.0f);
          xout[(size_t)(rb[p] + q * 4 + r) * 64 + jt * 16 + m16] = __float2half(v);
          myl[(q * 4 + r) * 68 + jt * 16 + m16] = v;
        }
    }
#pragma unroll
    for (int p = 0; p < 2; ++p) lds_tr(lds[wv][p], m16, q, t0[p], t1[p]);
#pragma unroll
    for (int p = 0; p < 2; ++p)
#pragma unroll
      for (int jt = 0; jt < 4; ++jt) {
        acc[p][jt] = zero4();
        acc[p][jt] = MFMA(t0[p], wa[jt * 2 + 0], acc[p][jt]);
        acc[p][jt] = MFMA(t1[p], wa[jt * 2 + 1], acc[p][jt]);
      }
#pragma unroll
    for (int p = 0; p < 2; ++p) {
      float* myl = lds[wv][p];
#pragma unroll
      for (int jt = 0; jt < 4; ++jt)
#pragma unroll
        for (int r = 0; r < 4; ++r)
          myl[(q * 4 + r) * 68 + jt * 16 + m16] = fmaxf(acc[p][jt][r] + ba[jt], 0.0f);
    }
#pragma unroll
    for (int p = 0; p < 2; ++p) lds_tr(lds[wv][p], m16, q, t0[p], t1[p]);
#pragma unroll
    for (int p = 0; p < 2; ++p)
#pragma unroll
      for (int jt = 0; jt < 4; ++jt) {
        acc[p][jt] = zero4();
        acc[p][jt] = MFMA(t0[p], wb[jt * 2 + 0], acc[p][jt]);
        acc[p][jt] = MFMA(t1[p], wb[jt * 2 + 1], acc[p][jt]);
      }
#pragma unroll
    for (int p = 0; p < 2; ++p)
#pragma unroll
      for (int jt = 0; jt < 4; ++jt)
#pragma unroll
        for (int r = 0; r < 4; ++r)
          h[(size_t)(rb[p] + q * 4 + r) * 64 + jt * 16 + m16] =
              __float2half(acc[p][jt][r] + bb[jt]);
  }
}

// ---- fused: layer-2 catmm_w3 + classifier, 2-tile interleave ----
__global__ void __launch_bounds__(256) fused_cat_cls(const __half* __restrict__ xin,
    const __half* __restrict__ z, const __half* __restrict__ x0,
    const int* __restrict__ roff, const _Float16* __restrict__ wbuf,
    const float* __restrict__ b2, const float* __restrict__ b3,
    const float* __restrict__ bc1, const float* __restrict__ bc2,
    __half* __restrict__ out) {
  __shared__ float lds[4][2][16 * 68];
  int l = threadIdx.x & 63, q = l >> 4, m16 = l & 15, wv = threadIdx.x >> 6;
  int wid = (blockIdx.x * blockDim.x + threadIdx.x) >> 6;
  int nw = (gridDim.x * blockDim.x) >> 6;
  const h8* w2p = (const h8*)(wbuf + OFF_W2);
  const h8* w3p = (const h8*)(wbuf + OFF_W3);
  const h8* wc1p = (const h8*)(wbuf + OFF_C1);
  const h8* wc2p = (const h8*)(wbuf + OFF_C2);
  h8 w2[16], w3[8], wc1[8], wc2[4];
#pragma unroll
  for (int f = 0; f < 16; ++f) w2[f] = w2p[f * 64 + l];
#pragma unroll
  for (int f = 0; f < 8; ++f) { w3[f] = w3p[f * 64 + l]; wc1[f] = wc1p[f * 64 + l]; }
#pragma unroll
  for (int f = 0; f < 4; ++f) wc2[f] = wc2p[f * 64 + l];
  float bv2[4], bv3[4], bv1[4], bvo[2];
#pragma unroll
  for (int jt = 0; jt < 4; ++jt) {
    bv2[jt] = b2[jt * 16 + m16]; bv3[jt] = b3[jt * 16 + m16]; bv1[jt] = bc1[jt * 16 + m16];
  }
#pragma unroll
  for (int jt = 0; jt < 2; ++jt) bvo[jt] = bc2[jt * 16 + m16];
  for (int t = wid; t < HALF; t += nw) {
    int rb[2] = {t * 16, (t + HALF) * 16};
    h8 a0[2], a1[2], az0[2], az1[2];
#pragma unroll
    for (int p = 0; p < 2; ++p) {
      const __half* rp = xin + (size_t)(rb[p] + m16) * 64 + q * 8;
      a0[p] = *(const h8*)rp; a1[p] = *(const h8*)(rp + 32);
      const __half* zr = z + (size_t)(rb[p] + m16) * 64;
      az0[p] = *(const h8*)(zr + q * 8); az1[p] = *(const h8*)(zr + 32 + q * 8);
    }
    f4 acc[2][4];
#pragma unroll
    for (int p = 0; p < 2; ++p)
#pragma unroll
      for (int jt = 0; jt < 4; ++jt) {
        acc[p][jt] = zero4();
        acc[p][jt] = MFMA(a0[p],  w2[jt * 4 + 0], acc[p][jt]);
        acc[p][jt] = MFMA(a1[p],  w2[jt * 4 + 1], acc[p][jt]);
        acc[p][jt] = MFMA(az0[p], w2[jt * 4 + 2], acc[p][jt]);
        acc[p][jt] = MFMA(az1[p], w2[jt * 4 + 3], acc[p][jt]);
      }
#pragma unroll
    for (int p = 0; p < 2; ++p) {
      float* myl = lds[wv][p];
#pragma unroll
      for (int r = 0; r < 4; ++r) {
        int row = rb[p] + q * 4 + r;
        float msk = (roff[row + 1] > roff[row]) ? 0.5f : 0.0f;
#pragma unroll
        for (int jt = 0; jt < 4; ++jt) {
          float val = acc[p][jt][r] + bv2[jt];
          float x0v = __half2float(x0[(size_t)row * 64 + jt * 16 + m16]);
          myl[(q * 4 + r) * 68 + jt * 16 + m16] = fmaf(msk, val, 0.5f * x0v);
        }
      }
    }
    h8 t0[2], t1[2];
#pragma unroll
    for (int p = 0; p < 2; ++p) lds_tr(lds[wv][p], m16, q, t0[p], t1[p]);
#pragma unroll
    for (int p = 0; p < 2; ++p)
#pragma unroll
      for (int jt = 0; jt < 4; ++jt) {
        acc[p][jt] = zero4();
        acc[p][jt] = MFMA(t0[p], w3[jt * 2 + 0], acc[p][jt]);
        acc[p][jt] = MFMA(t1[p], w3[jt * 2 + 1], acc[p][jt]);
      }
#pragma unroll
    for (int p = 0; p < 2; ++p) {
      float* myl = lds[wv][p];
#pragma unroll
      for (int jt = 0; jt < 4; ++jt)
#pragma unroll
        for (int r = 0; r < 4; ++r)
          myl[(q * 4 + r) * 68 + jt * 16 + m16] = fmaxf(acc[p][jt][r] + bv3[jt], 0.0f);
    }
#pragma unroll
    for (int p = 0; p < 2; ++p) lds_tr(lds[wv][p], m16, q, t0[p], t1[p]);
#pragma unroll
    for (int p = 0; p < 2; ++p)
#pragma unroll
      for (int jt = 0; jt < 4; ++jt) {
        acc[p][jt] = zero4();
        acc[p][jt] = MFMA(t0[p], wc1[jt * 2 + 0], acc[p][jt]);
        acc[p][jt] = MFMA(t1[p], wc1[jt * 2 + 1], acc[p][jt]);
      }
#pragma unroll
    for (int p = 0; p < 2; ++p) {
      float* myl = lds[wv][p];
#pragma unroll
      for (int jt = 0; jt < 4; ++jt)
#pragma unroll
        for (int r = 0; r < 4; ++r)
          myl[(q * 4 + r) * 68 + jt * 16 + m16] = fmaxf(acc[p][jt][r] + bv1[jt], 0.0f);
    }
#pragma unroll
    for (int p = 0; p < 2; ++p) lds_tr(lds[wv][p], m16, q, t0[p], t1[p]);
    f4 o[2][2];
#pragma unroll
    for (int p = 0; p < 2; ++p)
#pragma unroll
      for (int jt = 0; jt < 2; ++jt) {
        o[p][jt] = zero4();
        o[p][jt] = MFMA(t0[p], wc2[jt * 2 + 0], o[p][jt]);
        o[p][jt] = MFMA(t1[p], wc2[jt * 2 + 1], o[p][jt]);
      }
#pragma unroll
    for (int p = 0; p < 2; ++p)
#pragma unroll
      for (int jt = 0; jt < 2; ++jt)
#pragma unroll
        for (int r = 0; r < 4; ++r)
          out[(size_t)(rb[p] + q * 4 + r) * 32 + jt * 16 + m16] =
              __float2half(o[p][jt][r] + bvo[jt]);
  }
}

// ---- per-graph mean readout; fp16 input ----
__global__ void __launch_bounds__(256) readout_k(const __half* __restrict__ xc,
    const int* __restrict__ batch, int n, float* __restrict__ out) {
  __shared__ float part[8][32];
  int g = blockIdx.x;
  int lo = lbound(batch, n, g);
  int hi = lbound(batch, n, g + 1);
  int j = threadIdx.x & 31, r = threadIdx.x >> 5;
  float acc = 0.0f;
  for (int i = lo + r; i < hi; i += 8) acc += __half2float(xc[(size_t)i * 32 + j]);
  part[r][j] = acc;
  __syncthreads();
  if (threadIdx.x < 32) {
    float s = 0.0f;
#pragma unroll
    for (int rr = 0; rr < 8; ++rr) s += part[rr][j];
    out[g * 32 + j] = (hi > lo) ? s / (float)(hi - lo) : 0.0f;
  }
}

extern "C" void kernel_launch(void* const* d_in, const int* in_sizes, int n_in,
                              void* d_out, int out_size, void* d_ws, size_t ws_size,
                              hipStream_t stream) {
  const float* X    = (const float*)d_in[0];
  const int*   src  = (const int*)d_in[1];
  const int*   dst  = (const int*)d_in[2];
  const int*   batch= (const int*)d_in[3];
  const float* W_in = (const float*)d_in[4];
  const float* b_in = (const float*)d_in[5];
  const float* W1a  = (const float*)d_in[6];
  const float* b1a  = (const float*)d_in[7];
  const float* W1b  = (const float*)d_in[8];
  const float* b1b  = (const float*)d_in[9];
  const float* W2   = (const float*)d_in[10];
  const float* b2   = (const float*)d_in[11];
  const float* W3   = (const float*)d_in[12];
  const float* b3   = (const float*)d_in[13];
  const float* Wc1  = (const float*)d_in[14];
  const float* bc1  = (const float*)d_in[15];
  const float* Wc2  = (const float*)d_in[16];
  const float* bc2  = (const float*)d_in[17];
  float* out = (float*)d_out;

  // workspace layout (~57 MB)
  float* p  = (float*)d_ws;
  __half* xA = (__half*)p; p += (size_t)NN * 32;       // x0 / layer-1 x
  __half* xB = (__half*)p; p += (size_t)NN * 32;       // layer-1 out / layer-2 x
  __half* hz = (__half*)p; p += (size_t)NN * 32 + 32;  // h/z + zero row NN
  __half* Xe = (__half*)p; p += (size_t)NE * 32 + 32;  // Xe + zero row NE; outc at end
  float* invE = p; p += NE;
  _Float16* wbuf = (_Float16*)p; p += WBUF_HALVES / 2 + 16;
  int* q     = (int*)p;
  int* off   = q; q += NE + 1;
  int* bcnt  = q; q += 256;
  int* roff  = q; q += NN + 1;
  int* csr   = q; q += NZ;        // 5.12 MB
  unsigned int* words = (unsigned int*)q; q += CB * CAP;  // 6.4 MB
  __half* h = hz;
  __half* z = hz;            // alias: h fully consumed before z written
  __half* outc = Xe;         // alias: Xe dead after layer-2 zgather

  // bcnt zero (stream-ordered; graph-capture-safe), then merged prep+binA
  hipMemsetAsync(bcnt, 0, 256 * sizeof(int), stream);
  prep_binA_k<<<NBLK_ROW + 69 + NBLK_A, 256, 0, stream>>>(src, dst, roff, bcnt,
      words, NN, NZ, W_in, W1a, W1b, W2, W3, Wc1, Wc2, wbuf, hz, Xe);

  // binB || layer-1 front half (x=x0=xA, h) in one dispatch
  binB_indual_k<<<CB + MMGRID, 256, 0, stream>>>(words, bcnt, off, invE, csr,
      X, wbuf, b_in, b1a, b1b, xA, h);

  ve_pull_k<<<(NE * 8 + 255) / 256, 256, 0, stream>>>(h, csr, off, invE, Xe, NE);
  zgather_k<<<(NN * 8 + 255) / 256, 256, 0, stream>>>(Xe, dst, roff, z, NN);

  // layer-1 back half + layer-2 front half (2-tile interleaved)
  fused_cat_dual<<<MMGRID, 256, 0, stream>>>(xA, z, xA, roff, wbuf, b2, b3,
                                             b1a, b1b, xB, h);
  ve_pull_k<<<(NE * 8 + 255) / 256, 256, 0, stream>>>(h, csr, off, invE, Xe, NE);
  zgather_k<<<(NN * 8 + 255) / 256, 256, 0, stream>>>(Xe, dst, roff, z, NN);

  // layer-2 back half + classifier (2-tile interleaved): logits to outc
  fused_cat_cls<<<MMGRID, 256, 0, stream>>>(xB, z, xA, roff, wbuf, b2, b3,
                                            bc1, bc2, outc);
  readout_k<<<NG, 256, 0, stream>>>(outc, batch, NN, out);
}

// Round 9
// 302.225 us; speedup vs baseline: 1.4948x; 1.0666x over previous
//
#include <hip/hip_runtime.h>
#include <hip/hip_fp16.h>

// EquivSetGNN forward, MI355X.
// R22: revert R21's 2-tile interleave (322us: doubled reg/LDS state hurt more
// than the 2nd latency chain helped). Base = R18 (303us) with two safe deltas:
//  (1) prep_misc + binA merged (R21's merge; bcnt via hipMemsetAsync) — one
//      fewer dispatch boundary.
//  (2) fused_cat_dual: layer-1 has xin==x0, so the residual's 16 scalar 2B
//      global loads/tile/lane are replaced by reusing a0/a1: pre-fill LDS
//      with 0.5*x0 (4 f4 writes, A-layout), C-layout step becomes LDS RMW.
//      Removes ~1.6M scalar VMEM requests (request-rate pressure, cf. R19).

constexpr int NN = 100000;   // nodes
constexpr int NE = 50000;    // hyperedges
constexpr int NZ = 1280000;  // incidences
constexpr int NG = 256;      // graphs
constexpr int NTILE = NN / 16;  // 6250 row-tiles of 16
constexpr int CB = 196;         // coarse buckets
constexpr int CAP = 8192;       // bucket region capacity (words)
constexpr int CHUNK = 4000;
constexpr int NBLK_A = NZ / CHUNK;          // 320
constexpr int NBLK_ROW = (NZ + 255) / 256;  // 5000
constexpr int MMGRID = 1024;                // 4 blocks/CU exactly

typedef _Float16 h8 __attribute__((ext_vector_type(8)));
typedef float f4 __attribute__((ext_vector_type(4)));

constexpr int OFF_IN  = 0;
constexpr int OFF_1A  = 8192;
constexpr int OFF_1B  = 12288;
constexpr int OFF_W2  = 16384;
constexpr int OFF_W3  = 24576;
constexpr int OFF_C1  = 28672;
constexpr int OFF_C2  = 32768;
constexpr int WBUF_HALVES = 34816;

__device__ __forceinline__ int lbound(const int* a, int n, int v) {
  int lo = 0, hi = n;
  while (lo < hi) { int m = (lo + hi) >> 1; if (a[m] < v) lo = m + 1; else hi = m; }
  return lo;
}

__device__ __forceinline__ f4 zero4() { f4 z; z[0]=0.f; z[1]=0.f; z[2]=0.f; z[3]=0.f; return z; }

__device__ __forceinline__ h8 ld_a32(const float* p) {
  const f4* v = (const f4*)p;
  f4 lo = v[0], hi = v[1];
  h8 r;
  r[0]=(_Float16)lo[0]; r[1]=(_Float16)lo[1]; r[2]=(_Float16)lo[2]; r[3]=(_Float16)lo[3];
  r[4]=(_Float16)hi[0]; r[5]=(_Float16)hi[1]; r[6]=(_Float16)hi[2]; r[7]=(_Float16)hi[3];
  return r;
}

// LDS transpose read: lane gets row m16, cols q*8..q*8+7 (t0) and +32 (t1),
// via four aligned f4 vector loads (2-way bank alias only -> conflict-free).
__device__ __forceinline__ void lds_tr(const float* __restrict__ myl, int m16, int q,
                                       h8& t0, h8& t1) {
  const f4* rp = (const f4*)(myl + m16 * 68);
  f4 u0 = rp[q * 2], u1 = rp[q * 2 + 1];
  f4 u2 = rp[8 + q * 2], u3 = rp[8 + q * 2 + 1];
#pragma unroll
  for (int j = 0; j < 4; ++j) {
    t0[j] = (_Float16)u0[j]; t0[j + 4] = (_Float16)u1[j];
    t1[j] = (_Float16)u2[j]; t1[j + 4] = (_Float16)u3[j];
  }
}

#define MFMA(a, b, c) __builtin_amdgcn_mfma_f32_16x16x32_f16((a), (b), (c), 0, 0, 0)

// ---- merged: roff | weight prep | dummy-row zero | binA chunks ----
// bcnt must be zeroed before launch (hipMemsetAsync).
__global__ void __launch_bounds__(256) prep_binA_k(const int* __restrict__ src,
    const int* __restrict__ dst, int* __restrict__ roff, int* __restrict__ bcnt,
    unsigned int* __restrict__ words, int n, int nnz,
    const float* __restrict__ W_in, const float* __restrict__ W1a,
    const float* __restrict__ W1b, const float* __restrict__ W2,
    const float* __restrict__ W3,  const float* __restrict__ Wc1,
    const float* __restrict__ Wc2, _Float16* __restrict__ wbuf,
    __half* __restrict__ hz, __half* __restrict__ Xe) {
  __shared__ int cnt[CB];
  __shared__ int base[CB];
  int blk = blockIdx.x;
  if (blk < NBLK_ROW) {
    int i = blk * 256 + threadIdx.x;
    if (i >= nnz) return;
    int s = src[i];
    int prev = (i == 0) ? -1 : src[i - 1];
    for (int v = prev + 1; v <= s; ++v) roff[v] = i;
    if (i == nnz - 1) {
      for (int v = s + 1; v <= n; ++v) roff[v] = nnz;
    }
    return;
  }
  int b = blk - NBLK_ROW;
  if (b < 68) {
    int l = threadIdx.x;
    if (l >= 64) return;
    const float* srcw; int K, J; _Float16* dstw; int tile;
    if      (b < 16) { srcw = W_in; K = 128; J = 64; dstw = wbuf + OFF_IN; tile = b; }
    else if (b < 24) { srcw = W1a;  K = 64;  J = 64; dstw = wbuf + OFF_1A; tile = b - 16; }
    else if (b < 32) { srcw = W1b;  K = 64;  J = 64; dstw = wbuf + OFF_1B; tile = b - 24; }
    else if (b < 48) { srcw = W2;   K = 128; J = 64; dstw = wbuf + OFF_W2; tile = b - 32; }
    else if (b < 56) { srcw = W3;   K = 64;  J = 64; dstw = wbuf + OFF_W3; tile = b - 48; }
    else if (b < 64) { srcw = Wc1;  K = 64;  J = 64; dstw = wbuf + OFF_C1; tile = b - 56; }
    else             { srcw = Wc2;  K = 64;  J = 32; dstw = wbuf + OFF_C2; tile = b - 64; }
    int KS = K / 32;
    int jt = tile / KS, ks = tile % KS;
    int q = l >> 4, m = l & 15;
#pragma unroll
    for (int j = 0; j < 8; ++j)
      dstw[((size_t)tile * 64 + l) * 8 + j] =
          (_Float16)srcw[(size_t)(ks * 32 + q * 8 + j) * J + jt * 16 + m];
    return;
  }
  if (b == 68) {
    int t = threadIdx.x;
    if (t < 32) ((float*)(hz + (size_t)NN * 64))[t] = 0.0f;            // h dummy row NN
    else if (t < 64) ((float*)(Xe + (size_t)NE * 64))[t - 32] = 0.0f;  // Xe dummy row NE
    return;
  }
  // ---- binA chunk ----
  int c = b - 69;
  int t = threadIdx.x;
  int start = c * CHUNK;
  for (int i = t; i < CB; i += 256) cnt[i] = 0;
  __syncthreads();
  for (int i = start + t; i < start + CHUNK; i += 256)
    atomicAdd(&cnt[dst[i] >> 8], 1);
  __syncthreads();
  for (int i = t; i < CB; i += 256) base[i] = atomicAdd(&bcnt[i], cnt[i]);
  __syncthreads();
  for (int i = t; i < CB; i += 256) cnt[i] = 0;  // reuse as cursor
  __syncthreads();
  for (int i = start + t; i < start + CHUNK; i += 256) {
    int d = dst[i];
    int bb2 = d >> 8;
    int p = base[bb2] + atomicAdd(&cnt[bb2], 1);
    words[(size_t)bb2 * CAP + p] = (unsigned)src[i] | ((unsigned)(d & 255) << 24);
  }
}

// ---- merged: binB (blocks<CB) || fused_in_dual (blocks>=CB) ----
union MergedSMem {
  struct { int buf[CAP]; int hist[256]; int sh[256]; int cur[256]; int shb[256]; } b;
  float myl[4][16 * 68];
};

__global__ void __launch_bounds__(256) binB_indual_k(
    const unsigned int* __restrict__ words, const int* __restrict__ bcnt,
    int* __restrict__ off, float* __restrict__ invE, int* __restrict__ csr,
    const float* __restrict__ A, const _Float16* __restrict__ wbuf,
    const float* __restrict__ b_in, const float* __restrict__ b1a,
    const float* __restrict__ b1b, __half* __restrict__ x, __half* __restrict__ h) {
  __shared__ MergedSMem sm;
  if (blockIdx.x < CB) {
    int b = blockIdx.x, t = threadIdx.x;
    int e0 = b << 8;
    int ecnt = min(256, NE - e0);
    int cntb = bcnt[b];
    sm.b.shb[t] = (t < CB) ? bcnt[t] : 0;
    __syncthreads();
    for (int ofs = 1; ofs < 256; ofs <<= 1) {
      int v = (t >= ofs) ? sm.b.shb[t - ofs] : 0;
      __syncthreads();
      sm.b.shb[t] += v;
      __syncthreads();
    }
    int gbase = sm.b.shb[b] - cntb;
    const unsigned int* wp = words + (size_t)b * CAP;
    sm.b.hist[t] = 0;
    __syncthreads();
    for (int i = t; i < cntb; i += 256) atomicAdd(&sm.b.hist[wp[i] >> 24], 1);
    __syncthreads();
    int c = sm.b.hist[t];
    sm.b.sh[t] = c;
    __syncthreads();
    for (int ofs = 1; ofs < 256; ofs <<= 1) {
      int v = (t >= ofs) ? sm.b.sh[t - ofs] : 0;
      __syncthreads();
      sm.b.sh[t] += v;
      __syncthreads();
    }
    int excl = sm.b.sh[t] - c;
    if (t < ecnt) {
      off[e0 + t] = gbase + excl;
      invE[e0 + t] = 1.0f / (float)max(c, 1);
    }
    if (b == CB - 1 && t == 0) off[NE] = NZ;
    sm.b.cur[t] = excl;
    __syncthreads();
    for (int i = t; i < cntb; i += 256) {
      unsigned w = wp[i];
      int s = (int)(w & 0xFFFFFFu);
      int p = atomicAdd(&sm.b.cur[w >> 24], 1);
      if (p < CAP) sm.b.buf[p] = s;
      else csr[gbase + p] = s;  // statistically never
    }
    __syncthreads();
    int lim = min(cntb, CAP);
    for (int i = t; i < lim; i += 256) csr[gbase + i] = sm.b.buf[i];
    return;
  }
  // ---- fused_in_dual branch ----
  int l = threadIdx.x & 63, q = l >> 4, m16 = l & 15, wv = threadIdx.x >> 6;
  int wid = ((blockIdx.x - CB) * 256 + (int)threadIdx.x) >> 6;
  int nw = (MMGRID * 256) >> 6;
  const h8* wip = (const h8*)(wbuf + OFF_IN);
  const h8* wap = (const h8*)(wbuf + OFF_1A);
  const h8* wbp = (const h8*)(wbuf + OFF_1B);
  h8 wi[16], wa[8], wb[8];
#pragma unroll
  for (int f = 0; f < 16; ++f) wi[f] = wip[f * 64 + l];
#pragma unroll
  for (int f = 0; f < 8; ++f) { wa[f] = wap[f * 64 + l]; wb[f] = wbp[f * 64 + l]; }
  float bi[4], ba[4], bb[4];
#pragma unroll
  for (int jt = 0; jt < 4; ++jt) {
    bi[jt] = b_in[jt * 16 + m16]; ba[jt] = b1a[jt * 16 + m16]; bb[jt] = b1b[jt * 16 + m16];
  }
  float* myl = sm.myl[wv];
  for (int t = wid; t < NTILE; t += nw) {
    int rbase = t * 16;
    const float* rp = A + (size_t)(rbase + m16) * 128 + q * 8;
    h8 a0 = ld_a32(rp), a1 = ld_a32(rp + 32), a2 = ld_a32(rp + 64), a3 = ld_a32(rp + 96);
    f4 acc[4];
#pragma unroll
    for (int jt = 0; jt < 4; ++jt) {
      acc[jt] = zero4();
      acc[jt] = MFMA(a0, wi[jt * 4 + 0], acc[jt]);
      acc[jt] = MFMA(a1, wi[jt * 4 + 1], acc[jt]);
      acc[jt] = MFMA(a2, wi[jt * 4 + 2], acc[jt]);
      acc[jt] = MFMA(a3, wi[jt * 4 + 3], acc[jt]);
    }
#pragma unroll
    for (int jt = 0; jt < 4; ++jt)
#pragma unroll
      for (int r = 0; r < 4; ++r) {
        float v = fmaxf(acc[jt][r] + bi[jt], 0.0f);
        x[(size_t)(rbase + q * 4 + r) * 64 + jt * 16 + m16] = __float2half(v);
        myl[(q * 4 + r) * 68 + jt * 16 + m16] = v;
      }
    h8 t0, t1;
    lds_tr(myl, m16, q, t0, t1);
#pragma unroll
    for (int jt = 0; jt < 4; ++jt) {
      acc[jt] = zero4();
      acc[jt] = MFMA(t0, wa[jt * 2 + 0], acc[jt]);
      acc[jt] = MFMA(t1, wa[jt * 2 + 1], acc[jt]);
    }
#pragma unroll
    for (int jt = 0; jt < 4; ++jt)
#pragma unroll
      for (int r = 0; r < 4; ++r)
        myl[(q * 4 + r) * 68 + jt * 16 + m16] = fmaxf(acc[jt][r] + ba[jt], 0.0f);
    lds_tr(myl, m16, q, t0, t1);
#pragma unroll
    for (int jt = 0; jt < 4; ++jt) {
      acc[jt] = zero4();
      acc[jt] = MFMA(t0, wb[jt * 2 + 0], acc[jt]);
      acc[jt] = MFMA(t1, wb[jt * 2 + 1], acc[jt]);
    }
#pragma unroll
    for (int jt = 0; jt < 4; ++jt)
#pragma unroll
      for (int r = 0; r < 4; ++r)
        h[(size_t)(rbase + q * 4 + r) * 64 + jt * 16 + m16] = __float2half(acc[jt][r] + bb[jt]);
  }
}

// ---- pipelined segment-mean gather core ----
__device__ __forceinline__ void segmean_pf(const __half* __restrict__ rows,
    const int* __restrict__ idxArr, int lo, int hi, int zrow, float inv,
    __half* __restrict__ outp, int gid, int c) {
  float acc[8];
#pragma unroll
  for (int j = 0; j < 8; ++j) acc[j] = 0.0f;
  int n = hi - lo;
  if (n > 0) {
    int lim = hi - 1;
    int i = lo;
    int j0 = idxArr[i];
    int j1 = idxArr[min(i + 1, lim)]; j1 = (i + 1 <= lim) ? j1 : zrow;
    int j2 = idxArr[min(i + 2, lim)]; j2 = (i + 2 <= lim) ? j2 : zrow;
    int j3 = idxArr[min(i + 3, lim)]; j3 = (i + 3 <= lim) ? j3 : zrow;
    int nb = (n + 3) >> 2;
    for (int b = 0; b < nb; ++b) {
      h8 v0 = *(const h8*)(rows + (size_t)j0 * 64 + c * 8);
      h8 v1 = *(const h8*)(rows + (size_t)j1 * 64 + c * 8);
      h8 v2 = *(const h8*)(rows + (size_t)j2 * 64 + c * 8);
      h8 v3 = *(const h8*)(rows + (size_t)j3 * 64 + c * 8);
      i += 4;
      int n0 = idxArr[min(i, lim)];     n0 = (i     <= lim) ? n0 : zrow;
      int n1 = idxArr[min(i + 1, lim)]; n1 = (i + 1 <= lim) ? n1 : zrow;
      int n2 = idxArr[min(i + 2, lim)]; n2 = (i + 2 <= lim) ? n2 : zrow;
      int n3 = idxArr[min(i + 3, lim)]; n3 = (i + 3 <= lim) ? n3 : zrow;
#pragma unroll
      for (int j = 0; j < 8; ++j)
        acc[j] += ((float)v0[j] + (float)v1[j]) + ((float)v2[j] + (float)v3[j]);
      j0 = n0; j1 = n1; j2 = n2; j3 = n3;
    }
  }
  h8 o;
#pragma unroll
  for (int j = 0; j < 8; ++j) o[j] = (_Float16)(acc[j] * inv);
  *(h8*)(outp + (size_t)gid * 64 + c * 8) = o;
}

// ---- V->E pull: 8-lane group per edge, 128B row reads ----
__global__ void __launch_bounds__(256) ve_pull_k(const __half* __restrict__ h,
    const int* __restrict__ csr, const int* __restrict__ off,
    const float* __restrict__ invE, __half* __restrict__ Xe, int e) {
  int gid = (blockIdx.x * blockDim.x + threadIdx.x) >> 3;
  if (gid >= e) return;
  int c = threadIdx.x & 7;
  segmean_pf(h, csr, off[gid], off[gid + 1], NN, invE[gid], Xe, gid, c);
}

// ---- E->V pull: 8-lane group per node ----
__global__ void __launch_bounds__(256) zgather_k(const __half* __restrict__ Xe,
    const int* __restrict__ dstArr, const int* __restrict__ roff,
    __half* __restrict__ z, int n) {
  int gid = (blockIdx.x * blockDim.x + threadIdx.x) >> 3;
  if (gid >= n) return;
  int c = threadIdx.x & 7;
  int lo = roff[gid], hi = roff[gid + 1];
  float inv = (hi > lo) ? 1.0f / (float)(hi - lo) : 0.0f;
  segmean_pf(Xe, dstArr, lo, hi, NE, inv, z, gid, c);
}

// ---- fused: layer-1 catmm_w3 + layer-2 W1 MLP. REQUIRES xin == x0 (layer 1):
// residual 0.5*x0 comes from the already-loaded a0/a1 via LDS pre-fill, not
// from 16 scalar global loads. ----
__global__ void __launch_bounds__(256) fused_cat_dual(const __half* __restrict__ xin,
    const __half* __restrict__ z,
    const int* __restrict__ roff, const _Float16* __restrict__ wbuf,
    const float* __restrict__ b2, const float* __restrict__ b3,
    const float* __restrict__ b1a, const float* __restrict__ b1b,
    __half* __restrict__ xout, __half* __restrict__ h, int ntiles) {
  __shared__ float lds[4][16 * 68];
  int l = threadIdx.x & 63, q = l >> 4, m16 = l & 15, wv = threadIdx.x >> 6;
  int wid = (blockIdx.x * blockDim.x + threadIdx.x) >> 6;
  int nw = (gridDim.x * blockDim.x) >> 6;
  const h8* w2p = (const h8*)(wbuf + OFF_W2);
  const h8* w3p = (const h8*)(wbuf + OFF_W3);
  const h8* wap = (const h8*)(wbuf + OFF_1A);
  const h8* wbp = (const h8*)(wbuf + OFF_1B);
  h8 w2[16], w3[8], wa[8], wb[8];
#pragma unroll
  for (int f = 0; f < 16; ++f) w2[f] = w2p[f * 64 + l];
#pragma unroll
  for (int f = 0; f < 8; ++f) { w3[f] = w3p[f * 64 + l]; wa[f] = wap[f * 64 + l]; wb[f] = wbp[f * 64 + l]; }
  float bv2[4], bv3[4], ba[4], bb[4];
#pragma unroll
  for (int jt = 0; jt < 4; ++jt) {
    bv2[jt] = b2[jt * 16 + m16]; bv3[jt] = b3[jt * 16 + m16];
    ba[jt] = b1a[jt * 16 + m16]; bb[jt] = b1b[jt * 16 + m16];
  }
  float* myl = lds[wv];
  for (int t = wid; t < ntiles; t += nw) {
    int rbase = t * 16;
    const __half* rp = xin + (size_t)(rbase + m16) * 64 + q * 8;
    h8 a0 = *(const h8*)rp, a1 = *(const h8*)(rp + 32);
    const __half* zr = z + (size_t)(rbase + m16) * 64;
    h8 az0 = *(const h8*)(zr + q * 8), az1 = *(const h8*)(zr + 32 + q * 8);
    // pre-fill myl with 0.5*x0 (x0 == xin; rows already in a0/a1), A-layout
    {
      f4 w0, w1, w2f, w3f;
#pragma unroll
      for (int j = 0; j < 4; ++j) {
        w0[j] = 0.5f * (float)a0[j];     w1[j] = 0.5f * (float)a0[j + 4];
        w2f[j] = 0.5f * (float)a1[j];    w3f[j] = 0.5f * (float)a1[j + 4];
      }
      f4* wp = (f4*)(myl + m16 * 68 + q * 8);
      wp[0] = w0; wp[1] = w1;
      f4* wp2 = (f4*)(myl + m16 * 68 + 32 + q * 8);
      wp2[0] = w2f; wp2[1] = w3f;
    }
    f4 acc[4];
#pragma unroll
    for (int jt = 0; jt < 4; ++jt) {
      acc[jt] = zero4();
      acc[jt] = MFMA(a0,  w2[jt * 4 + 0], acc[jt]);
      acc[jt] = MFMA(a1,  w2[jt * 4 + 1], acc[jt]);
      acc[jt] = MFMA(az0, w2[jt * 4 + 2], acc[jt]);
      acc[jt] = MFMA(az1, w2[jt * 4 + 3], acc[jt]);
    }
#pragma unroll
    for (int r = 0; r < 4; ++r) {
      int row = rbase + q * 4 + r;
      float msk = (roff[row + 1] > roff[row]) ? 0.5f : 0.0f;
#pragma unroll
      for (int jt = 0; jt < 4; ++jt) {
        float val = acc[jt][r] + bv2[jt];
        int idx = (q * 4 + r) * 68 + jt * 16 + m16;
        myl[idx] = fmaf(msk, val, myl[idx]);   // += over pre-filled 0.5*x0
      }
    }
    h8 t0, t1;
    lds_tr(myl, m16, q, t0, t1);
#pragma unroll
    for (int jt = 0; jt < 4; ++jt) {
      acc[jt] = zero4();
      acc[jt] = MFMA(t0, w3[jt * 2 + 0], acc[jt]);
      acc[jt] = MFMA(t1, w3[jt * 2 + 1], acc[jt]);
    }
#pragma unroll
    for (int jt = 0; jt < 4; ++jt)
#pragma unroll
      for (int r = 0; r < 4; ++r) {
        float v = fmaxf(acc[jt][r] + bv3[jt], 0.0f);
        xout[(size_t)(rbase + q * 4 + r) * 64 + jt * 16 + m16] = __float2half(v);
        myl[(q * 4 + r) * 68 + jt * 16 + m16] = v;
      }
    lds_tr(myl, m16, q, t0, t1);
#pragma unroll
    for (int jt = 0; jt < 4; ++jt) {
      acc[jt] = zero4();
      acc[jt] = MFMA(t0, wa[jt * 2 + 0], acc[jt]);
      acc[jt] = MFMA(t1, wa[jt * 2 + 1], acc[jt]);
    }
#pragma unroll
    for (int jt = 0; jt < 4; ++jt)
#pragma unroll
      for (int r = 0; r < 4; ++r)
        myl[(q * 4 + r) * 68 + jt * 16 + m16] = fmaxf(acc[jt][r] + ba[jt], 0.0f);
    lds_tr(myl, m16, q, t0, t1);
#pragma unroll
    for (int jt = 0; jt < 4; ++jt) {
      acc[jt] = zero4();
      acc[jt] = MFMA(t0, wb[jt * 2 + 0], acc[jt]);
      acc[jt] = MFMA(t1, wb[jt * 2 + 1], acc[jt]);
    }
#pragma unroll
    for (int jt = 0; jt < 4; ++jt)
#pragma unroll
      for (int r = 0; r < 4; ++r)
        h[(size_t)(rbase + q * 4 + r) * 64 + jt * 16 + m16] = __float2half(acc[jt][r] + bb[jt]);
  }
}

// ---- fused: layer-2 catmm_w3 + classifier (x0 != xin -> scalar x0 loads) ----
__global__ void __launch_bounds__(256) fused_cat_cls(const __half* __restrict__ xin,
    const __half* __restrict__ z, const __half* __restrict__ x0,
    const int* __restrict__ roff, const _Float16* __restrict__ wbuf,
    const float* __restrict__ b2, const float* __restrict__ b3,
    const float* __restrict__ bc1, const float* __restrict__ bc2,
    __half* __restrict__ out, int ntiles) {
  __shared__ float lds[4][16 * 68];
  int l = threadIdx.x & 63, q = l >> 4, m16 = l & 15, wv = threadIdx.x >> 6;
  int wid = (blockIdx.x * blockDim.x + threadIdx.x) >> 6;
  int nw = (gridDim.x * blockDim.x) >> 6;
  const h8* w2p = (const h8*)(wbuf + OFF_W2);
  const h8* w3p = (const h8*)(wbuf + OFF_W3);
  const h8* wc1p = (const h8*)(wbuf + OFF_C1);
  const h8* wc2p = (const h8*)(wbuf + OFF_C2);
  h8 w2[16], w3[8], wc1[8], wc2[4];
#pragma unroll
  for (int f = 0; f < 16; ++f) w2[f] = w2p[f * 64 + l];
#pragma unroll
  for (int f = 0; f < 8; ++f) { w3[f] = w3p[f * 64 + l]; wc1[f] = wc1p[f * 64 + l]; }
#pragma unroll
  for (int f = 0; f < 4; ++f) wc2[f] = wc2p[f * 64 + l];
  float bv2[4], bv3[4], bv1[4], bvo[2];
#pragma unroll
  for (int jt = 0; jt < 4; ++jt) {
    bv2[jt] = b2[jt * 16 + m16]; bv3[jt] = b3[jt * 16 + m16]; bv1[jt] = bc1[jt * 16 + m16];
  }
#pragma unroll
  for (int jt = 0; jt < 2; ++jt) bvo[jt] = bc2[jt * 16 + m16];
  float* myl = lds[wv];
  for (int t = wid; t < ntiles; t += nw) {
    int rbase = t * 16;
    const __half* rp = xin + (size_t)(rbase + m16) * 64 + q * 8;
    h8 a0 = *(const h8*)rp, a1 = *(const h8*)(rp + 32);
    const __half* zr = z + (size_t)(rbase + m16) * 64;
    h8 az0 = *(const h8*)(zr + q * 8), az1 = *(const h8*)(zr + 32 + q * 8);
    f4 acc[4];
#pragma unroll
    for (int jt = 0; jt < 4; ++jt) {
      acc[jt] = zero4();
      acc[jt] = MFMA(a0,  w2[jt * 4 + 0], acc[jt]);
      acc[jt] = MFMA(a1,  w2[jt * 4 + 1], acc[jt]);
      acc[jt] = MFMA(az0, w2[jt * 4 + 2], acc[jt]);
      acc[jt] = MFMA(az1, w2[jt * 4 + 3], acc[jt]);
    }
#pragma unroll
    for (int r = 0; r < 4; ++r) {
      int row = rbase + q * 4 + r;
      float msk = (roff[row + 1] > roff[row]) ? 0.5f : 0.0f;
#pragma unroll
      for (int jt = 0; jt < 4; ++jt) {
        float val = acc[jt][r] + bv2[jt];
        float x0v = __half2float(x0[(size_t)row * 64 + jt * 16 + m16]);
        myl[(q * 4 + r) * 68 + jt * 16 + m16] = fmaf(msk, val, 0.5f * x0v);
      }
    }
    h8 t0, t1;
    lds_tr(myl, m16, q, t0, t1);
#pragma unroll
    for (int jt = 0; jt < 4; ++jt) {
      acc[jt] = zero4();
      acc[jt] = MFMA(t0, w3[jt * 2 + 0], acc[jt]);
      acc[jt] = MFMA(t1, w3[jt * 2 + 1], acc[jt]);
    }
#pragma unroll
    for (int jt = 0; jt < 4; ++jt)
#pragma unroll
      for (int r = 0; r < 4; ++r)
        myl[(q * 4 + r) * 68 + jt * 16 + m16] = fmaxf(acc[jt][r] + bv3[jt], 0.0f);
    lds_tr(myl, m16, q, t0, t1);
#pragma unroll
    for (int jt = 0; jt < 4; ++jt) {
      acc[jt] = zero4();
      acc[jt] = MFMA(t0, wc1[jt * 2 + 0], acc[jt]);
      acc[jt] = MFMA(t1, wc1[jt * 2 + 1], acc[jt]);
    }
#pragma unroll
    for (int jt = 0; jt < 4; ++jt)
#pragma unroll
      for (int r = 0; r < 4; ++r)
        myl[(q * 4 + r) * 68 + jt * 16 + m16] = fmaxf(acc[jt][r] + bv1[jt], 0.0f);
    lds_tr(myl, m16, q, t0, t1);
    f4 o[2];
#pragma unroll
    for (int jt = 0; jt < 2; ++jt) {
      o[jt] = zero4();
      o[jt] = MFMA(t0, wc2[jt * 2 + 0], o[jt]);
      o[jt] = MFMA(t1, wc2[jt * 2 + 1], o[jt]);
    }
#pragma unroll
    for (int jt = 0; jt < 2; ++jt)
#pragma unroll
      for (int r = 0; r < 4; ++r)
        out[(size_t)(rbase + q * 4 + r) * 32 + jt * 16 + m16] =
            __float2half(o[jt][r] + bvo[jt]);
  }
}

// ---- per-graph mean readout; fp16 input ----
__global__ void __launch_bounds__(256) readout_k(const __half* __restrict__ xc,
    const int* __restrict__ batch, int n, float* __restrict__ out) {
  __shared__ float part[8][32];
  int g = blockIdx.x;
  int lo = lbound(batch, n, g);
  int hi = lbound(batch, n, g + 1);
  int j = threadIdx.x & 31, r = threadIdx.x >> 5;
  float acc = 0.0f;
  for (int i = lo + r; i < hi; i += 8) acc += __half2float(xc[(size_t)i * 32 + j]);
  part[r][j] = acc;
  __syncthreads();
  if (threadIdx.x < 32) {
    float s = 0.0f;
#pragma unroll
    for (int rr = 0; rr < 8; ++rr) s += part[rr][j];
    out[g * 32 + j] = (hi > lo) ? s / (float)(hi - lo) : 0.0f;
  }
}

extern "C" void kernel_launch(void* const* d_in, const int* in_sizes, int n_in,
                              void* d_out, int out_size, void* d_ws, size_t ws_size,
                              hipStream_t stream) {
  const float* X    = (const float*)d_in[0];
  const int*   src  = (const int*)d_in[1];
  const int*   dst  = (const int*)d_in[2];
  const int*   batch= (const int*)d_in[3];
  const float* W_in = (const float*)d_in[4];
  const float* b_in = (const float*)d_in[5];
  const float* W1a  = (const float*)d_in[6];
  const float* b1a  = (const float*)d_in[7];
  const float* W1b  = (const float*)d_in[8];
  const float* b1b  = (const float*)d_in[9];
  const float* W2   = (const float*)d_in[10];
  const float* b2   = (const float*)d_in[11];
  const float* W3   = (const float*)d_in[12];
  const float* b3   = (const float*)d_in[13];
  const float* Wc1  = (const float*)d_in[14];
  const float* bc1  = (const float*)d_in[15];
  const float* Wc2  = (const float*)d_in[16];
  const float* bc2  = (const float*)d_in[17];
  float* out = (float*)d_out;

  // workspace layout (~57 MB)
  float* p  = (float*)d_ws;
  __half* xA = (__half*)p; p += (size_t)NN * 32;       // x0 / layer-1 x
  __half* xB = (__half*)p; p += (size_t)NN * 32;       // layer-1 out / layer-2 x
  __half* hz = (__half*)p; p += (size_t)NN * 32 + 32;  // h/z + zero row NN
  __half* Xe = (__half*)p; p += (size_t)NE * 32 + 32;  // Xe + zero row NE; outc at end
  float* invE = p; p += NE;
  _Float16* wbuf = (_Float16*)p; p += WBUF_HALVES / 2 + 16;
  int* q     = (int*)p;
  int* off   = q; q += NE + 1;
  int* bcnt  = q; q += 256;
  int* roff  = q; q += NN + 1;
  int* csr   = q; q += NZ;        // 5.12 MB
  unsigned int* words = (unsigned int*)q; q += CB * CAP;  // 6.4 MB
  __half* h = hz;
  __half* z = hz;            // alias: h fully consumed before z written
  __half* outc = Xe;         // alias: Xe dead after layer-2 zgather

  // bcnt zero (stream-ordered; graph-capture-safe), then merged prep+binA
  hipMemsetAsync(bcnt, 0, 256 * sizeof(int), stream);
  prep_binA_k<<<NBLK_ROW + 69 + NBLK_A, 256, 0, stream>>>(src, dst, roff, bcnt,
      words, NN, NZ, W_in, W1a, W1b, W2, W3, Wc1, Wc2, wbuf, hz, Xe);

  // binB || layer-1 front half (x=x0=xA, h) in one dispatch
  binB_indual_k<<<CB + MMGRID, 256, 0, stream>>>(words, bcnt, off, invE, csr,
      X, wbuf, b_in, b1a, b1b, xA, h);

  ve_pull_k<<<(NE * 8 + 255) / 256, 256, 0, stream>>>(h, csr, off, invE, Xe, NE);
  zgather_k<<<(NN * 8 + 255) / 256, 256, 0, stream>>>(Xe, dst, roff, z, NN);

  // layer-1 back half + layer-2 front half (xin == x0 == xA)
  fused_cat_dual<<<MMGRID, 256, 0, stream>>>(xA, z, roff, wbuf, b2, b3, b1a, b1b,
                                             xB, h, NTILE);
  ve_pull_k<<<(NE * 8 + 255) / 256, 256, 0, stream>>>(h, csr, off, invE, Xe, NE);
  zgather_k<<<(NN * 8 + 255) / 256, 256, 0, stream>>>(Xe, dst, roff, z, NN);

  // layer-2 back half + classifier: logits to outc
  fused_cat_cls<<<MMGRID, 256, 0, stream>>>(xB, z, xA, roff, wbuf, b2, b3, bc1, bc2,
                                            outc, NTILE);
  readout_k<<<NG, 256, 0, stream>>>(outc, batch, NN, out);
}